// Round 1
// baseline (898.002 us; speedup 1.0000x reference)
//
#include <hip/hip_runtime.h>
#include <math.h>

#define B_    2
#define C_    512
#define H_    64
#define W_    32
#define S_    2048      // H_*W_
#define QKC_  576       // C_ + 64 emb channels
#define INNER_ 512
#define NH_   8
#define HD_   64
#define TWO_PI_ 6.283185307179586f

// ---------------- build X[:, 0:512] = transpose(hidden) ----------------
// X layout: [B*S, QKC_] row-major. hidden: [B, C, S].
__global__ void k_transpose_in(const float* __restrict__ hid, float* __restrict__ X) {
    __shared__ float t[32][33];
    int b  = blockIdx.z;
    int s0 = blockIdx.x * 32, c0 = blockIdx.y * 32;
    int tx = threadIdx.x, ty = threadIdx.y;
    // coalesced read along s
    t[ty][tx] = hid[((size_t)b * C_ + (c0 + ty)) * S_ + s0 + tx];
    __syncthreads();
    // coalesced write along c
    X[((size_t)(b * S_ + s0 + ty)) * QKC_ + c0 + tx] = t[tx][ty];
}

// ---------------- X[:, 512:576] = embeddings ----------------
__global__ void k_emb(float* __restrict__ X) {
    int idx = blockIdx.x * blockDim.x + threadIdx.x;   // over B_*S_*64 = 2^18
    if (idx >= B_ * S_ * 64) return;
    int c = idx & 63;
    int s = (idx >> 6) & (S_ - 1);
    int b = idx >> 17;
    int h = s >> 5;        // s / W_
    int w = s & 31;        // s % W_
    float val;
    if (c < 32) {
        // freq: f = c>>1; arg = (f+1)*log2(h*16+f), with (h=0,f=0) -> log2 := -2
        int f = c >> 1;
        int n = h * 16 + f;
        float lx = (n == 0) ? -2.0f : log2f((float)n);
        float arg = lx * (float)(f + 1);
        val = (c & 1) ? sinf(arg) : cosf(arg);
    } else {
        // time: t = (c-32)>>1; theta = (t+0.5)*(w*16+t)/512 * 2pi
        int t = (c - 32) >> 1;
        float theta = ((float)t + 0.5f) * (float)(w * 16 + t) * (TWO_PI_ / 512.0f);
        val = (c & 1) ? sinf(theta) : cosf(theta);
    }
    X[(size_t)(b * S_ + s) * QKC_ + 512 + c] = val;
}

// ---------------- fp32 tiled GEMM: C[M,N] = A[M,K](lda) @ Bw[K,N] (+bias) ----------------
// 64x64 tile, 256 threads, 4x4 per thread, BK=16
__global__ __launch_bounds__(256) void k_gemm(const float* __restrict__ A,
                                              const float* __restrict__ Bw,
                                              const float* __restrict__ bias,
                                              float* __restrict__ Cout,
                                              int M, int N, int K, int lda) {
    __shared__ float As[16][68];   // As[k][m]
    __shared__ float Bs[16][68];   // Bs[k][n]
    int tid = threadIdx.x;
    int tx = tid & 15, ty = tid >> 4;
    int n0 = blockIdx.x * 64, m0 = blockIdx.y * 64;
    float acc[4][4] = {};
    for (int k0 = 0; k0 < K; k0 += 16) {
        #pragma unroll
        for (int i = 0; i < 4; i++) {
            int r  = (tid >> 4) + i * 16;   // m within tile
            int cc = tid & 15;              // k within tile
            As[cc][r] = A[(size_t)(m0 + r) * lda + k0 + cc];
        }
        #pragma unroll
        for (int i = 0; i < 4; i++) {
            int r  = (tid >> 6) + i * 4;    // k within tile
            int cc = tid & 63;              // n within tile
            Bs[r][cc] = Bw[(size_t)(k0 + r) * N + n0 + cc];
        }
        __syncthreads();
        #pragma unroll
        for (int kk = 0; kk < 16; kk++) {
            float4 a4 = *(const float4*)&As[kk][ty * 4];
            float4 b4 = *(const float4*)&Bs[kk][tx * 4];
            float a[4]  = {a4.x, a4.y, a4.z, a4.w};
            float bb[4] = {b4.x, b4.y, b4.z, b4.w};
            #pragma unroll
            for (int i = 0; i < 4; i++)
                #pragma unroll
                for (int j = 0; j < 4; j++)
                    acc[i][j] += a[i] * bb[j];
        }
        __syncthreads();
    }
    #pragma unroll
    for (int i = 0; i < 4; i++) {
        int m = m0 + ty * 4 + i;
        float4 v;
        float* vp = &v.x;
        #pragma unroll
        for (int j = 0; j < 4; j++) {
            int n = n0 + tx * 4 + j;
            vp[j] = acc[i][j] + (bias ? bias[n] : 0.0f);
        }
        *(float4*)&Cout[(size_t)m * N + n0 + tx * 4] = v;
    }
}

// ---------------- flash attention, fp32 ----------------
// block = (b, h, q-block of 64 rows); 256 threads (tx=tid&15, ty=tid>>4)
// thread owns q rows {ty+16i}, cols {tx+16j} of each 64x64 tile
__global__ __launch_bounds__(256) void k_attn(const float* __restrict__ Qf,
                                              const float* __restrict__ Kf,
                                              const float* __restrict__ Vf,
                                              float* __restrict__ Of) {
    __shared__ float Qs[64][68];    // [q][d]
    __shared__ float KPs[64][68];   // K tile [k][d], then reused as P tile [q][k]
    __shared__ float Vt[64][68];    // V tile transposed [d][k]

    int qb = blockIdx.x, h = blockIdx.y, b = blockIdx.z;
    int tid = threadIdx.x;
    int tx = tid & 15, ty = tid >> 4;

    const size_t qrow0 = (size_t)(b * S_ + qb * 64);
    const int hoff = h * HD_;

    #pragma unroll
    for (int p = 0; p < 16; p++) {
        int idx = p * 256 + tid;
        int r = idx >> 6, d = idx & 63;
        Qs[r][d] = Qf[(qrow0 + r) * INNER_ + hoff + d];
    }

    float m[4], l[4], accO[4][4];
    #pragma unroll
    for (int i = 0; i < 4; i++) {
        m[i] = -INFINITY; l[i] = 0.0f;
        #pragma unroll
        for (int j = 0; j < 4; j++) accO[i][j] = 0.0f;
    }

    for (int kt = 0; kt < S_ / 64; kt++) {
        __syncthreads();   // prev iter's reads of KPs/Vt complete
        size_t krow0 = (size_t)(b * S_ + kt * 64);
        #pragma unroll
        for (int p = 0; p < 16; p++) {
            int idx = p * 256 + tid;
            int r = idx >> 6, d = idx & 63;
            float kv = Kf[(krow0 + r) * INNER_ + hoff + d];
            float vv = Vf[(krow0 + r) * INNER_ + hoff + d];
            KPs[r][d] = kv;
            Vt[d][r]  = vv;
        }
        __syncthreads();

        // scores s[i][j] = sum_d Q[ty+16i][d] * K[tx+16j][d]
        float s[4][4] = {};
        #pragma unroll
        for (int d0 = 0; d0 < 16; d0++) {
            float4 qa[4], kb4[4];
            #pragma unroll
            for (int i = 0; i < 4; i++) qa[i] = *(const float4*)&Qs[ty + 16 * i][d0 * 4];
            #pragma unroll
            for (int j = 0; j < 4; j++) kb4[j] = *(const float4*)&KPs[tx + 16 * j][d0 * 4];
            #pragma unroll
            for (int i = 0; i < 4; i++)
                #pragma unroll
                for (int j = 0; j < 4; j++)
                    s[i][j] += qa[i].x * kb4[j].x + qa[i].y * kb4[j].y
                             + qa[i].z * kb4[j].z + qa[i].w * kb4[j].w;
        }
        __syncthreads();   // all lanes done reading K tile before overwriting with P

        // online softmax (scale = 1/sqrt(64) = 0.125)
        #pragma unroll
        for (int i = 0; i < 4; i++) {
            #pragma unroll
            for (int j = 0; j < 4; j++) s[i][j] *= 0.125f;
            float tm = fmaxf(fmaxf(s[i][0], s[i][1]), fmaxf(s[i][2], s[i][3]));
            tm = fmaxf(tm, __shfl_xor(tm, 1));
            tm = fmaxf(tm, __shfl_xor(tm, 2));
            tm = fmaxf(tm, __shfl_xor(tm, 4));
            tm = fmaxf(tm, __shfl_xor(tm, 8));
            float mn = fmaxf(m[i], tm);
            float corr = __expf(m[i] - mn);
            float ts = 0.0f;
            #pragma unroll
            for (int j = 0; j < 4; j++) {
                float p = __expf(s[i][j] - mn);
                s[i][j] = p;
                ts += p;
            }
            ts += __shfl_xor(ts, 1);
            ts += __shfl_xor(ts, 2);
            ts += __shfl_xor(ts, 4);
            ts += __shfl_xor(ts, 8);
            l[i] = l[i] * corr + ts;
            m[i] = mn;
            #pragma unroll
            for (int j = 0; j < 4; j++) {
                accO[i][j] *= corr;
                KPs[ty + 16 * i][tx + 16 * j] = s[i][j];   // P tile
            }
        }
        __syncthreads();

        // accO[i][j] += sum_k P[ty+16i][k] * V[k][tx+16j]
        #pragma unroll
        for (int k0 = 0; k0 < 16; k0++) {
            float4 pv[4], vv4[4];
            #pragma unroll
            for (int i = 0; i < 4; i++) pv[i]  = *(const float4*)&KPs[ty + 16 * i][k0 * 4];
            #pragma unroll
            for (int j = 0; j < 4; j++) vv4[j] = *(const float4*)&Vt[tx + 16 * j][k0 * 4];
            #pragma unroll
            for (int i = 0; i < 4; i++)
                #pragma unroll
                for (int j = 0; j < 4; j++)
                    accO[i][j] += pv[i].x * vv4[j].x + pv[i].y * vv4[j].y
                                + pv[i].z * vv4[j].z + pv[i].w * vv4[j].w;
        }
    }

    #pragma unroll
    for (int i = 0; i < 4; i++) {
        float inv = 1.0f / l[i];
        #pragma unroll
        for (int j = 0; j < 4; j++)
            Of[(qrow0 + ty + 16 * i) * INNER_ + hoff + tx + 16 * j] = accO[i][j] * inv;
    }
}

// ---------------- out = transpose(O2) + hidden ----------------
__global__ void k_out(const float* __restrict__ O2, const float* __restrict__ hid,
                      float* __restrict__ out) {
    __shared__ float t[32][33];
    int b  = blockIdx.z;
    int s0 = blockIdx.x * 32, c0 = blockIdx.y * 32;
    int tx = threadIdx.x, ty = threadIdx.y;
    t[ty][tx] = O2[(size_t)(b * S_ + s0 + ty) * C_ + c0 + tx];   // coalesced over c
    __syncthreads();
    size_t o = ((size_t)b * C_ + c0 + ty) * S_ + s0 + tx;        // coalesced over s
    out[o] = t[tx][ty] + hid[o];
}

extern "C" void kernel_launch(void* const* d_in, const int* in_sizes, int n_in,
                              void* d_out, int out_size, void* d_ws, size_t ws_size,
                              hipStream_t stream) {
    const float* hid  = (const float*)d_in[0];
    const float* Wq   = (const float*)d_in[1];
    const float* Wk   = (const float*)d_in[2];
    const float* Wv   = (const float*)d_in[3];
    const float* Wout = (const float*)d_in[4];
    const float* bout = (const float*)d_in[5];
    float* out = (float*)d_out;

    float* ws = (float*)d_ws;
    float* X  = ws;                               // [B*S, 576]
    float* Q  = X  + (size_t)B_ * S_ * QKC_;      // [B*S, 512]
    float* Kb = Q  + (size_t)B_ * S_ * INNER_;    // [B*S, 512]
    float* Vb = Kb + (size_t)B_ * S_ * INNER_;    // [B*S, 512]
    float* O  = Vb + (size_t)B_ * S_ * INNER_;    // [B*S, 512]
    float* O2 = X;                                // reuse X region: [B*S, 512]

    const int M = B_ * S_;   // 4096

    k_transpose_in<<<dim3(S_ / 32, C_ / 32, B_), dim3(32, 32), 0, stream>>>(hid, X);
    k_emb<<<(B_ * S_ * 64) / 256, 256, 0, stream>>>(X);

    k_gemm<<<dim3(INNER_ / 64, M / 64), 256, 0, stream>>>(X, Wq, nullptr, Q,  M, INNER_, QKC_, QKC_);
    k_gemm<<<dim3(INNER_ / 64, M / 64), 256, 0, stream>>>(X, Wk, nullptr, Kb, M, INNER_, QKC_, QKC_);
    k_gemm<<<dim3(INNER_ / 64, M / 64), 256, 0, stream>>>(X, Wv, nullptr, Vb, M, INNER_, C_,   QKC_);

    k_attn<<<dim3(S_ / 64, NH_, B_), 256, 0, stream>>>(Q, Kb, Vb, O);

    k_gemm<<<dim3(C_ / 64, M / 64), 256, 0, stream>>>(O, Wout, bout, O2, M, C_, INNER_, INNER_);

    k_out<<<dim3(S_ / 32, C_ / 32, B_), dim3(32, 32), 0, stream>>>(O2, hid, out);
}

// Round 2
// 148.963 us; speedup vs baseline: 6.0284x; 6.0284x over previous
//
#include <hip/hip_runtime.h>
#include <math.h>

#define B_    2
#define C_    512
#define H_    64
#define W_    32
#define S_    2048
#define QKC_  576
#define INNER_ 512
#define NH_   8
#define HD_   64
#define TWO_PI_ 6.283185307179586f

typedef __attribute__((ext_vector_type(8))) short bfrag;
typedef __attribute__((ext_vector_type(4))) float ffrag;

__device__ __forceinline__ ushort f2bf(float f) {
    unsigned u = __builtin_bit_cast(unsigned, f);
    unsigned r = (u + 0x7FFFu + ((u >> 16) & 1u)) >> 16;
    return (ushort)r;
}

// ---------------- X[:, 0:512] = transpose(hidden) as bf16 ----------------
__global__ void k_transpose_in(const float* __restrict__ hid, ushort* __restrict__ X) {
    __shared__ float t[32][33];
    int b  = blockIdx.z;
    int s0 = blockIdx.x * 32, c0 = blockIdx.y * 32;
    int tx = threadIdx.x, ty = threadIdx.y;
    t[ty][tx] = hid[((size_t)b * C_ + (c0 + ty)) * S_ + s0 + tx];
    __syncthreads();
    X[((size_t)(b * S_ + s0 + ty)) * QKC_ + c0 + tx] = f2bf(t[tx][ty]);
}

// ---------------- X[:, 512:576] = embeddings (bf16) ----------------
__global__ void k_emb(ushort* __restrict__ X) {
    int idx = blockIdx.x * blockDim.x + threadIdx.x;
    if (idx >= B_ * S_ * 64) return;
    int c = idx & 63;
    int s = (idx >> 6) & (S_ - 1);
    int b = idx >> 17;
    int h = s >> 5;
    int w = s & 31;
    float val;
    if (c < 32) {
        int f = c >> 1;
        int n = h * 16 + f;
        float lx = (n == 0) ? -2.0f : log2f((float)n);
        float arg = lx * (float)(f + 1);
        val = (c & 1) ? sinf(arg) : cosf(arg);
    } else {
        int t = (c - 32) >> 1;
        float theta = ((float)t + 0.5f) * (float)(w * 16 + t) * (TWO_PI_ / 512.0f);
        val = (c & 1) ? sinf(theta) : cosf(theta);
    }
    X[(size_t)(b * S_ + s) * QKC_ + 512 + c] = f2bf(val);
}

// ---------------- W [K][N] fp32 -> Wt [N][K] bf16 ----------------
__global__ void k_wtrans(const float* __restrict__ W, ushort* __restrict__ Wt, int K, int N) {
    __shared__ float t[32][33];
    int k0 = blockIdx.x * 32, n0 = blockIdx.y * 32;
    int tx = threadIdx.x, ty = threadIdx.y;
    t[ty][tx] = W[(size_t)(k0 + ty) * N + n0 + tx];
    __syncthreads();
    Wt[(size_t)(n0 + ty) * K + k0 + tx] = f2bf(t[tx][ty]);
}

// ---------------- bf16 MFMA GEMM: C[M,N] = A[M,K](lda) @ Bt[N,K]^T ----------------
// BM=128, BN=64, BK=64; 256 threads = 4 waves (2x2); per wave 64x32 = acc[4][2]
// MODE 0: bf16 out [M][N];  MODE 1: bf16 out transposed Vt[(b*512+n)][2048] (M=B*S);
// MODE 2: fp32 out [M][N] + bias
template<int MODE>
__global__ __launch_bounds__(256) void k_gemm(const ushort* __restrict__ A, int lda,
                                              const ushort* __restrict__ Bt,
                                              const float* __restrict__ bias,
                                              void* __restrict__ Cout,
                                              int M, int N, int K) {
    __shared__ ushort smem[128 * 72 + 64 * 72];
    ushort (*As)[72] = (ushort(*)[72])smem;
    ushort (*Bs)[72] = (ushort(*)[72])(smem + 128 * 72);

    int tid = threadIdx.x;
    int l   = tid & 63;
    int wv  = tid >> 6;
    int wr  = wv >> 1, wc = wv & 1;
    int n0 = blockIdx.x * 64, m0 = blockIdx.y * 128;
    int l15 = l & 15, lg = l >> 4;

    ffrag acc[4][2];
    #pragma unroll
    for (int i = 0; i < 4; i++)
        #pragma unroll
        for (int j = 0; j < 2; j++) acc[i][j] = (ffrag){0.f, 0.f, 0.f, 0.f};

    for (int k0 = 0; k0 < K; k0 += 64) {
        __syncthreads();
        #pragma unroll
        for (int p = 0; p < 4; p++) {           // A tile: 128x64 = 1024 chunks of 8
            int c = tid + p * 256;
            int row = c >> 3, kc = c & 7;
            uint4 v = *(const uint4*)(A + (size_t)(m0 + row) * lda + k0 + kc * 8);
            *(uint4*)&As[row][kc * 8] = v;
        }
        #pragma unroll
        for (int p = 0; p < 2; p++) {           // B tile: 64x64 = 512 chunks
            int c = tid + p * 256;
            int row = c >> 3, kc = c & 7;
            uint4 v = *(const uint4*)(Bt + (size_t)(n0 + row) * K + k0 + kc * 8);
            *(uint4*)&Bs[row][kc * 8] = v;
        }
        __syncthreads();
        #pragma unroll
        for (int ks = 0; ks < 2; ks++) {
            bfrag af[4], bf[2];
            #pragma unroll
            for (int mi = 0; mi < 4; mi++)
                af[mi] = *(const bfrag*)&As[wr * 64 + mi * 16 + l15][ks * 32 + lg * 8];
            #pragma unroll
            for (int nj = 0; nj < 2; nj++)
                bf[nj] = *(const bfrag*)&Bs[wc * 32 + nj * 16 + l15][ks * 32 + lg * 8];
            #pragma unroll
            for (int mi = 0; mi < 4; mi++)
                #pragma unroll
                for (int nj = 0; nj < 2; nj++)
                    acc[mi][nj] = __builtin_amdgcn_mfma_f32_16x16x32_bf16(af[mi], bf[nj], acc[mi][nj], 0, 0, 0);
        }
    }

    if (MODE == 1) {
        // transpose epilogue through LDS, then coalesced write to Vt[(b*512+n)][2048]
        ushort (*Ct)[136] = (ushort(*)[136])smem;   // 64 x 128 (n x m), fits in As region
        __syncthreads();
        #pragma unroll
        for (int mi = 0; mi < 4; mi++)
            #pragma unroll
            for (int nj = 0; nj < 2; nj++)
                #pragma unroll
                for (int r = 0; r < 4; r++)
                    Ct[wc * 32 + nj * 16 + l15][wr * 64 + mi * 16 + lg * 4 + r] = f2bf(acc[mi][nj][r]);
        __syncthreads();
        ushort* Co = (ushort*)Cout;
        int b = m0 >> 11, s0 = m0 & 2047;
        #pragma unroll
        for (int p = 0; p < 4; p++) {
            int c = tid + p * 256;               // 64 x 16 chunks
            int rowc = c >> 4, mc = c & 15;
            uint4 v = *(uint4*)&Ct[rowc][mc * 8];
            *(uint4*)(Co + (((size_t)(b * 512 + n0 + rowc)) << 11) + s0 + mc * 8) = v;
        }
    } else {
        #pragma unroll
        for (int mi = 0; mi < 4; mi++)
            #pragma unroll
            for (int nj = 0; nj < 2; nj++)
                #pragma unroll
                for (int r = 0; r < 4; r++) {
                    int row = m0 + wr * 64 + mi * 16 + lg * 4 + r;
                    int col = n0 + wc * 32 + nj * 16 + l15;
                    if (MODE == 0)
                        ((ushort*)Cout)[(size_t)row * N + col] = f2bf(acc[mi][nj][r]);
                    else
                        ((float*)Cout)[(size_t)row * N + col] = acc[mi][nj][r] + bias[col];
                }
    }
}

// ---------------- flash attention, bf16 MFMA ----------------
// block = (qb, h, b); 256 threads = 4 waves; wave w owns q rows w*16..w*16+15
__global__ __launch_bounds__(256) void k_attn(const ushort* __restrict__ Qf,
                                              const ushort* __restrict__ Kf,
                                              const ushort* __restrict__ Vtg,
                                              ushort* __restrict__ Of) {
    __shared__ ushort Qs[64][72];
    __shared__ ushort Ks[64][72];
    __shared__ ushort Vt[64][72];   // [d][kk]
    __shared__ ushort Ps[64][72];

    int qb = blockIdx.x, h = blockIdx.y, b = blockIdx.z;
    int tid = threadIdx.x;
    int l = tid & 63, wv = tid >> 6;
    int l15 = l & 15, lg = l >> 4;
    const int hoff = h * HD_;
    const size_t qrow0 = (size_t)(b * S_ + qb * 64);

    #pragma unroll
    for (int p = 0; p < 2; p++) {
        int c = tid + p * 256;
        int r = c >> 3, dc = c & 7;
        uint4 v = *(const uint4*)(Qf + (qrow0 + r) * INNER_ + hoff + dc * 8);
        *(uint4*)&Qs[r][dc * 8] = v;
    }

    float mrow[4], lrow[4];
    ffrag accO[4];
    #pragma unroll
    for (int r = 0; r < 4; r++) { mrow[r] = -INFINITY; lrow[r] = 0.f; }
    #pragma unroll
    for (int fc = 0; fc < 4; fc++) accO[fc] = (ffrag){0.f, 0.f, 0.f, 0.f};

    for (int kt = 0; kt < S_ / 64; kt++) {
        __syncthreads();
        {
            size_t krow0 = (size_t)(b * S_ + kt * 64);
            const ushort* vbase = Vtg + (((size_t)(b * 512 + hoff)) << 11) + kt * 64;
            #pragma unroll
            for (int p = 0; p < 2; p++) {
                int c = tid + p * 256;
                int r = c >> 3, dc = c & 7;
                uint4 kv = *(const uint4*)(Kf + (krow0 + r) * INNER_ + hoff + dc * 8);
                *(uint4*)&Ks[r][dc * 8] = kv;
                // V^T tile: row = d (c>>3), col chunk = kk (c&7)
                uint4 vv = *(const uint4*)(vbase + ((size_t)r << 11) + dc * 8);
                *(uint4*)&Vt[r][dc * 8] = vv;
            }
        }
        __syncthreads();

        // S = Q K^T  (wave's 16 q-rows x 64 kk)
        ffrag sf[4];
        #pragma unroll
        for (int fc = 0; fc < 4; fc++) sf[fc] = (ffrag){0.f, 0.f, 0.f, 0.f};
        #pragma unroll
        for (int ks = 0; ks < 2; ks++) {
            bfrag qa = *(const bfrag*)&Qs[wv * 16 + l15][ks * 32 + lg * 8];
            #pragma unroll
            for (int fc = 0; fc < 4; fc++) {
                bfrag kb = *(const bfrag*)&Ks[fc * 16 + l15][ks * 32 + lg * 8];
                sf[fc] = __builtin_amdgcn_mfma_f32_16x16x32_bf16(qa, kb, sf[fc], 0, 0, 0);
            }
        }

        // online softmax per row r (rows lg*4+r of this wave's 16)
        #pragma unroll
        for (int r = 0; r < 4; r++) {
            float s0 = sf[0][r] * 0.125f, s1 = sf[1][r] * 0.125f;
            float s2 = sf[2][r] * 0.125f, s3 = sf[3][r] * 0.125f;
            float tm = fmaxf(fmaxf(s0, s1), fmaxf(s2, s3));
            tm = fmaxf(tm, __shfl_xor(tm, 1));
            tm = fmaxf(tm, __shfl_xor(tm, 2));
            tm = fmaxf(tm, __shfl_xor(tm, 4));
            tm = fmaxf(tm, __shfl_xor(tm, 8));
            float mn = fmaxf(mrow[r], tm);
            float corr = __expf(mrow[r] - mn);
            float p0 = __expf(s0 - mn), p1 = __expf(s1 - mn);
            float p2 = __expf(s2 - mn), p3 = __expf(s3 - mn);
            float ts = p0 + p1 + p2 + p3;
            ts += __shfl_xor(ts, 1);
            ts += __shfl_xor(ts, 2);
            ts += __shfl_xor(ts, 4);
            ts += __shfl_xor(ts, 8);
            lrow[r] = lrow[r] * corr + ts;
            mrow[r] = mn;
            #pragma unroll
            for (int fc = 0; fc < 4; fc++) accO[fc][r] *= corr;
            int prow = wv * 16 + lg * 4 + r;
            Ps[prow][0 * 16 + l15] = f2bf(p0);
            Ps[prow][1 * 16 + l15] = f2bf(p1);
            Ps[prow][2 * 16 + l15] = f2bf(p2);
            Ps[prow][3 * 16 + l15] = f2bf(p3);
        }
        __syncthreads();

        // O += P V   (A = P rows of this wave, B = V^T)
        #pragma unroll
        for (int ks = 0; ks < 2; ks++) {
            bfrag pa = *(const bfrag*)&Ps[wv * 16 + l15][ks * 32 + lg * 8];
            #pragma unroll
            for (int fc = 0; fc < 4; fc++) {
                bfrag vb = *(const bfrag*)&Vt[fc * 16 + l15][ks * 32 + lg * 8];
                accO[fc] = __builtin_amdgcn_mfma_f32_16x16x32_bf16(pa, vb, accO[fc], 0, 0, 0);
            }
        }
    }

    #pragma unroll
    for (int r = 0; r < 4; r++) {
        float inv = 1.0f / lrow[r];
        size_t row = qrow0 + wv * 16 + lg * 4 + r;
        #pragma unroll
        for (int fc = 0; fc < 4; fc++)
            Of[row * INNER_ + hoff + fc * 16 + l15] = f2bf(accO[fc][r] * inv);
    }
}

// ---------------- out = transpose(O2) + hidden ----------------
__global__ void k_out(const float* __restrict__ O2, const float* __restrict__ hid,
                      float* __restrict__ out) {
    __shared__ float t[32][33];
    int b  = blockIdx.z;
    int s0 = blockIdx.x * 32, c0 = blockIdx.y * 32;
    int tx = threadIdx.x, ty = threadIdx.y;
    t[ty][tx] = O2[(size_t)(b * S_ + s0 + ty) * C_ + c0 + tx];
    __syncthreads();
    size_t o = ((size_t)b * C_ + c0 + ty) * S_ + s0 + tx;
    out[o] = t[tx][ty] + hid[o];
}

extern "C" void kernel_launch(void* const* d_in, const int* in_sizes, int n_in,
                              void* d_out, int out_size, void* d_ws, size_t ws_size,
                              hipStream_t stream) {
    const float* hid  = (const float*)d_in[0];
    const float* Wq   = (const float*)d_in[1];
    const float* Wk   = (const float*)d_in[2];
    const float* Wv   = (const float*)d_in[3];
    const float* Wout = (const float*)d_in[4];
    const float* bout = (const float*)d_in[5];
    float* out = (float*)d_out;

    const int M = B_ * S_;   // 4096
    char* w = (char*)d_ws;
    ushort* X    = (ushort*)w;                    w += (size_t)M * QKC_ * 2;       // 4.7 MB
    ushort* Qb   = (ushort*)w;                    w += (size_t)M * INNER_ * 2;     // 4 MB
    ushort* Kbb  = (ushort*)w;                    w += (size_t)M * INNER_ * 2;
    ushort* Vtg  = (ushort*)w;                    w += (size_t)M * INNER_ * 2;     // [B*512][2048]
    ushort* Ob   = (ushort*)w;                    w += (size_t)M * INNER_ * 2;
    float*  O2   = (float*)w;                     w += (size_t)M * C_ * 4;         // 8 MB
    ushort* Wqt  = (ushort*)w;                    w += (size_t)INNER_ * QKC_ * 2;
    ushort* Wkt  = (ushort*)w;                    w += (size_t)INNER_ * QKC_ * 2;
    ushort* Wvt  = (ushort*)w;                    w += (size_t)INNER_ * C_ * 2;
    ushort* Wot  = (ushort*)w;                    w += (size_t)C_ * INNER_ * 2;

    k_wtrans<<<dim3(QKC_ / 32, INNER_ / 32), dim3(32, 32), 0, stream>>>(Wq, Wqt, QKC_, INNER_);
    k_wtrans<<<dim3(QKC_ / 32, INNER_ / 32), dim3(32, 32), 0, stream>>>(Wk, Wkt, QKC_, INNER_);
    k_wtrans<<<dim3(C_ / 32, INNER_ / 32), dim3(32, 32), 0, stream>>>(Wv, Wvt, C_, INNER_);
    k_wtrans<<<dim3(INNER_ / 32, C_ / 32), dim3(32, 32), 0, stream>>>(Wout, Wot, INNER_, C_);

    k_transpose_in<<<dim3(S_ / 32, C_ / 32, B_), dim3(32, 32), 0, stream>>>(hid, X);
    k_emb<<<(B_ * S_ * 64) / 256, 256, 0, stream>>>(X);

    k_gemm<0><<<dim3(INNER_ / 64, M / 128), 256, 0, stream>>>(X, QKC_, Wqt, nullptr, Qb,  M, INNER_, QKC_);
    k_gemm<0><<<dim3(INNER_ / 64, M / 128), 256, 0, stream>>>(X, QKC_, Wkt, nullptr, Kbb, M, INNER_, QKC_);
    k_gemm<1><<<dim3(INNER_ / 64, M / 128), 256, 0, stream>>>(X, QKC_, Wvt, nullptr, Vtg, M, INNER_, C_);

    k_attn<<<dim3(S_ / 64, NH_, B_), 256, 0, stream>>>(Qb, Kbb, Vtg, Ob);

    k_gemm<2><<<dim3(C_ / 64, M / 128), 256, 0, stream>>>(Ob, INNER_, Wot, bout, O2, M, C_, INNER_);

    k_out<<<dim3(S_ / 32, C_ / 32, B_), dim3(32, 32), 0, stream>>>(O2, hid, out);
}

// Round 3
// 148.656 us; speedup vs baseline: 6.0408x; 1.0021x over previous
//
#include <hip/hip_runtime.h>
#include <math.h>

#define B_    2
#define C_    512
#define H_    64
#define W_    32
#define S_    2048
#define QKC_  576
#define INNER_ 512
#define NH_   8
#define HD_   64
#define TWO_PI_ 6.283185307179586f

typedef __attribute__((ext_vector_type(8))) short bfrag;
typedef __attribute__((ext_vector_type(4))) float ffrag;
typedef __attribute__((ext_vector_type(16))) float f16v;

__device__ __forceinline__ ushort f2bf(float f) {
    unsigned u = __builtin_bit_cast(unsigned, f);
    unsigned r = (u + 0x7FFFu + ((u >> 16) & 1u)) >> 16;
    return (ushort)r;
}

__device__ __forceinline__ f16v zero16() {
    f16v z;
    #pragma unroll
    for (int i = 0; i < 16; i++) z[i] = 0.f;
    return z;
}

// ---------------- X[:, 0:512] = transpose(hidden) as bf16 ----------------
__global__ void k_transpose_in(const float* __restrict__ hid, ushort* __restrict__ X) {
    __shared__ float t[32][33];
    int b  = blockIdx.z;
    int s0 = blockIdx.x * 32, c0 = blockIdx.y * 32;
    int tx = threadIdx.x, ty = threadIdx.y;
    t[ty][tx] = hid[((size_t)b * C_ + (c0 + ty)) * S_ + s0 + tx];
    __syncthreads();
    X[((size_t)(b * S_ + s0 + ty)) * QKC_ + c0 + tx] = f2bf(t[tx][ty]);
}

// ---------------- X[:, 512:576] = embeddings (bf16) ----------------
__global__ void k_emb(ushort* __restrict__ X) {
    int idx = blockIdx.x * blockDim.x + threadIdx.x;
    if (idx >= B_ * S_ * 64) return;
    int c = idx & 63;
    int s = (idx >> 6) & (S_ - 1);
    int b = idx >> 17;
    int h = s >> 5;
    int w = s & 31;
    float val;
    if (c < 32) {
        int f = c >> 1;
        int n = h * 16 + f;
        float lx = (n == 0) ? -2.0f : log2f((float)n);
        float arg = lx * (float)(f + 1);
        val = (c & 1) ? sinf(arg) : cosf(arg);
    } else {
        int t = (c - 32) >> 1;
        float theta = ((float)t + 0.5f) * (float)(w * 16 + t) * (TWO_PI_ / 512.0f);
        val = (c & 1) ? sinf(theta) : cosf(theta);
    }
    X[(size_t)(b * S_ + s) * QKC_ + 512 + c] = f2bf(val);
}

// ---------------- W [K][N] fp32 -> Wt [N][K] bf16 ----------------
__global__ void k_wtrans(const float* __restrict__ W, ushort* __restrict__ Wt, int K, int N) {
    __shared__ float t[32][33];
    int k0 = blockIdx.x * 32, n0 = blockIdx.y * 32;
    int tx = threadIdx.x, ty = threadIdx.y;
    t[ty][tx] = W[(size_t)(k0 + ty) * N + n0 + tx];
    __syncthreads();
    Wt[(size_t)(n0 + ty) * K + k0 + tx] = f2bf(t[tx][ty]);
}

// ---------------- bf16 MFMA GEMM (unchanged from round 2) ----------------
template<int MODE>
__global__ __launch_bounds__(256) void k_gemm(const ushort* __restrict__ A, int lda,
                                              const ushort* __restrict__ Bt,
                                              const float* __restrict__ bias,
                                              void* __restrict__ Cout,
                                              int M, int N, int K) {
    __shared__ ushort smem[128 * 72 + 64 * 72];
    ushort (*As)[72] = (ushort(*)[72])smem;
    ushort (*Bs)[72] = (ushort(*)[72])(smem + 128 * 72);

    int tid = threadIdx.x;
    int l   = tid & 63;
    int wv  = tid >> 6;
    int wr  = wv >> 1, wc = wv & 1;
    int n0 = blockIdx.x * 64, m0 = blockIdx.y * 128;
    int l15 = l & 15, lg = l >> 4;

    ffrag acc[4][2];
    #pragma unroll
    for (int i = 0; i < 4; i++)
        #pragma unroll
        for (int j = 0; j < 2; j++) acc[i][j] = (ffrag){0.f, 0.f, 0.f, 0.f};

    for (int k0 = 0; k0 < K; k0 += 64) {
        __syncthreads();
        #pragma unroll
        for (int p = 0; p < 4; p++) {
            int c = tid + p * 256;
            int row = c >> 3, kc = c & 7;
            uint4 v = *(const uint4*)(A + (size_t)(m0 + row) * lda + k0 + kc * 8);
            *(uint4*)&As[row][kc * 8] = v;
        }
        #pragma unroll
        for (int p = 0; p < 2; p++) {
            int c = tid + p * 256;
            int row = c >> 3, kc = c & 7;
            uint4 v = *(const uint4*)(Bt + (size_t)(n0 + row) * K + k0 + kc * 8);
            *(uint4*)&Bs[row][kc * 8] = v;
        }
        __syncthreads();
        #pragma unroll
        for (int ks = 0; ks < 2; ks++) {
            bfrag af[4], bf[2];
            #pragma unroll
            for (int mi = 0; mi < 4; mi++)
                af[mi] = *(const bfrag*)&As[wr * 64 + mi * 16 + l15][ks * 32 + lg * 8];
            #pragma unroll
            for (int nj = 0; nj < 2; nj++)
                bf[nj] = *(const bfrag*)&Bs[wc * 32 + nj * 16 + l15][ks * 32 + lg * 8];
            #pragma unroll
            for (int mi = 0; mi < 4; mi++)
                #pragma unroll
                for (int nj = 0; nj < 2; nj++)
                    acc[mi][nj] = __builtin_amdgcn_mfma_f32_16x16x32_bf16(af[mi], bf[nj], acc[mi][nj], 0, 0, 0);
        }
    }

    if (MODE == 1) {
        ushort (*Ct)[136] = (ushort(*)[136])smem;
        __syncthreads();
        #pragma unroll
        for (int mi = 0; mi < 4; mi++)
            #pragma unroll
            for (int nj = 0; nj < 2; nj++)
                #pragma unroll
                for (int r = 0; r < 4; r++)
                    Ct[wc * 32 + nj * 16 + l15][wr * 64 + mi * 16 + lg * 4 + r] = f2bf(acc[mi][nj][r]);
        __syncthreads();
        ushort* Co = (ushort*)Cout;
        int b = m0 >> 11, s0 = m0 & 2047;
        #pragma unroll
        for (int p = 0; p < 4; p++) {
            int c = tid + p * 256;
            int rowc = c >> 4, mc = c & 15;
            uint4 v = *(uint4*)&Ct[rowc][mc * 8];
            *(uint4*)(Co + (((size_t)(b * 512 + n0 + rowc)) << 11) + s0 + mc * 8) = v;
        }
    } else {
        #pragma unroll
        for (int mi = 0; mi < 4; mi++)
            #pragma unroll
            for (int nj = 0; nj < 2; nj++)
                #pragma unroll
                for (int r = 0; r < 4; r++) {
                    int row = m0 + wr * 64 + mi * 16 + lg * 4 + r;
                    int col = n0 + wc * 32 + nj * 16 + l15;
                    if (MODE == 0)
                        ((ushort*)Cout)[(size_t)row * N + col] = f2bf(acc[mi][nj][r]);
                    else
                        ((float*)Cout)[(size_t)row * N + col] = acc[mi][nj][r] + bias[col];
                }
    }
}

// ---------------- flash attention: swapped QK^T, in-register softmax ----------------
// grid (32 qb, 8 h, 2 b); 256 thr = 4 waves. Wave w: q-sub wp=w>>1 (32 rows), KV-half h=w&1.
// LDS: 2(dbuf) x [half][K|VT] 64x64 bf16 tiles, XOR-swizzled (chunk ^= row&7). 64 KB.
#define CVTPK(dst, a, b) asm("v_cvt_pk_bf16_f32 %0, %1, %2" : "=v"(dst) : "v"(a), "v"(b))
#define SWAP32(a, b)     asm("v_permlane32_swap_b32 %0, %1" : "+v"(a), "+v"(b))

#define STAGE_LOAD(kt_) {                                                   \
    _Pragma("unroll")                                                       \
    for (int p = 0; p < 8; p++)                                             \
        st[p] = *(const uint4*)(sbase[p] + (size_t)(kt_) * sstr[p]); }

#define STAGE_WRITE(buf_) {                                                 \
    _Pragma("unroll")                                                       \
    for (int p = 0; p < 8; p++)                                             \
        *(uint4*)(ktv + (buf_) * 16384 + soff[p]) = st[p]; }

__global__ __launch_bounds__(256, 2) void k_attn(const ushort* __restrict__ Qf,
                                                 const ushort* __restrict__ Kf,
                                                 const ushort* __restrict__ Vtg,
                                                 ushort* __restrict__ Ob) {
    __shared__ ushort __attribute__((aligned(16))) ktv[2 * 4 * 4096];   // 64 KB
    __shared__ float mlsh[2][2][2][32];

    const int qb = blockIdx.x, hd = blockIdx.y, b = blockIdx.z;
    const int tid = threadIdx.x;
    const int l = tid & 63, wv = tid >> 6;
    const int wp = wv >> 1, hh = wv & 1;
    const int l31 = l & 31, hi = l >> 5, swz = l31 & 7;
    const int hoff = hd * HD_;
    const int brow = b * S_ + qb * 64;

    // Q fragments hoisted to registers (B-operand: lane holds q=l31, d-slice hi*8)
    bfrag qf[4];
    {
        const ushort* qp = Qf + (size_t)(brow + wp * 32 + l31) * INNER_ + hoff + hi * 8;
        #pragma unroll
        for (int ks = 0; ks < 4; ks++) qf[ks] = *(const bfrag*)(qp + ks * 16);
    }

    // staging precompute: 8 x 16B per thread covers 4 tiles (2 halves x {K, VT})
    const ushort* sbase[8];
    int sstr[8];
    unsigned soff[8];
    #pragma unroll
    for (int p = 0; p < 8; p++) {
        int f = p * 256 + tid;
        int T = f >> 9, hv = T >> 1, isV = T & 1;
        int r = (f >> 3) & 63, cc = f & 7;
        soff[p] = T * 4096 + r * 64 + ((cc ^ (r & 7)) * 8);
        if (isV) { sbase[p] = Vtg + (size_t)(b * 512 + hoff + r) * 2048 + hv * 1024 + cc * 8; sstr[p] = 64; }
        else     { sbase[p] = Kf + (size_t)(b * S_ + hv * 1024 + r) * INNER_ + hoff + cc * 8; sstr[p] = 64 * INNER_; }
    }

    uint4 st[8];
    STAGE_LOAD(0);
    STAGE_WRITE(0);
    __syncthreads();

    float m_run = -INFINITY, l_run = 0.f;
    f16v acc0 = zero16(), acc1 = zero16();
    int cur = 0;

    for (int kt = 0; kt < 16; kt++) {
        if (kt < 15) STAGE_LOAD(kt + 1);          // issue early (T14)

        const ushort* Kt  = ktv + cur * 16384 + hh * 8192;
        const ushort* Vtt = Kt + 4096;

        // ---- S = K Q^T (swapped): lane holds 32 scores for q = wp*32+l31 ----
        f16v sf0 = zero16(), sf1 = zero16();
        #pragma unroll
        for (int ks = 0; ks < 4; ks++) {
            int ch = ((ks * 2 + hi) ^ swz) * 8;
            bfrag k0 = *(const bfrag*)(Kt + l31 * 64 + ch);
            bfrag k1 = *(const bfrag*)(Kt + (l31 + 32) * 64 + ch);
            sf0 = __builtin_amdgcn_mfma_f32_32x32x16_bf16(k0, qf[ks], sf0, 0, 0, 0);
            sf1 = __builtin_amdgcn_mfma_f32_32x32x16_bf16(k1, qf[ks], sf1, 0, 0, 0);
        }

        // ---- online softmax, in-register (raw-score units; scale 0.125 folded in exp) ----
        float tm = -INFINITY;
        #pragma unroll
        for (int j = 0; j < 16; j++) { tm = fmaxf(tm, sf0[j]); tm = fmaxf(tm, sf1[j]); }
        tm = fmaxf(tm, __shfl_xor(tm, 32));
        if (!__all(tm <= m_run + 64.0f)) {        // defer-max: THR=8 nats (64 raw)
            float mn = fmaxf(m_run, tm);
            float corr = __expf((m_run - mn) * 0.125f);
            l_run *= corr;
            #pragma unroll
            for (int j = 0; j < 16; j++) { acc0[j] *= corr; acc1[j] *= corr; }
            m_run = mn;
        }
        float nm8 = -m_run * 0.125f;
        float ls = 0.f;
        #pragma unroll
        for (int j = 0; j < 16; j++) { float p = __expf(fmaf(sf0[j], 0.125f, nm8)); sf0[j] = p; ls += p; }
        #pragma unroll
        for (int j = 0; j < 16; j++) { float p = __expf(fmaf(sf1[j], 0.125f, nm8)); sf1[j] = p; ls += p; }
        ls += __shfl_xor(ls, 32);
        l_run += ls;

        // ---- O^T += V^T P  (A = V^T rows d, B = P cols q; q stays lane-local) ----
        #pragma unroll
        for (int s = 0; s < 2; s++) {             // k-slices 0,1 from sf0
            unsigned A0, B0, A1, B1;
            CVTPK(A0, sf0[s * 8 + 0], sf0[s * 8 + 1]); CVTPK(B0, sf0[s * 8 + 4], sf0[s * 8 + 5]);
            SWAP32(A0, B0);
            CVTPK(A1, sf0[s * 8 + 2], sf0[s * 8 + 3]); CVTPK(B1, sf0[s * 8 + 6], sf0[s * 8 + 7]);
            SWAP32(A1, B1);
            uint4 u; u.x = A0; u.y = A1; u.z = B0; u.w = B1;
            bfrag pa = __builtin_bit_cast(bfrag, u);
            int ch = ((s * 2 + hi) ^ swz) * 8;
            bfrag v0 = *(const bfrag*)(Vtt + l31 * 64 + ch);
            bfrag v1 = *(const bfrag*)(Vtt + (l31 + 32) * 64 + ch);
            acc0 = __builtin_amdgcn_mfma_f32_32x32x16_bf16(v0, pa, acc0, 0, 0, 0);
            acc1 = __builtin_amdgcn_mfma_f32_32x32x16_bf16(v1, pa, acc1, 0, 0, 0);
        }
        #pragma unroll
        for (int s = 0; s < 2; s++) {             // k-slices 2,3 from sf1
            unsigned A0, B0, A1, B1;
            CVTPK(A0, sf1[s * 8 + 0], sf1[s * 8 + 1]); CVTPK(B0, sf1[s * 8 + 4], sf1[s * 8 + 5]);
            SWAP32(A0, B0);
            CVTPK(A1, sf1[s * 8 + 2], sf1[s * 8 + 3]); CVTPK(B1, sf1[s * 8 + 6], sf1[s * 8 + 7]);
            SWAP32(A1, B1);
            uint4 u; u.x = A0; u.y = A1; u.z = B0; u.w = B1;
            bfrag pa = __builtin_bit_cast(bfrag, u);
            int ch = (((2 + s) * 2 + hi) ^ swz) * 8;
            bfrag v0 = *(const bfrag*)(Vtt + l31 * 64 + ch);
            bfrag v1 = *(const bfrag*)(Vtt + (l31 + 32) * 64 + ch);
            acc0 = __builtin_amdgcn_mfma_f32_32x32x16_bf16(v0, pa, acc0, 0, 0, 0);
            acc1 = __builtin_amdgcn_mfma_f32_32x32x16_bf16(v1, pa, acc1, 0, 0, 0);
        }

        __syncthreads();
        if (kt < 15) STAGE_WRITE(cur ^ 1);        // write late, after barrier
        __syncthreads();
        cur ^= 1;
    }

    // ---- combine the two KV-half partials per warp-pair, via LDS ----
    if (l < 32) { mlsh[wp][hh][0][l] = m_run; mlsh[wp][hh][1][l] = l_run; }
    __syncthreads();
    float mo  = mlsh[wp][hh ^ 1][0][l31];
    float lo_ = mlsh[wp][hh ^ 1][1][l31];
    float mn2 = fmaxf(m_run, mo);
    float cs  = __expf((m_run - mn2) * 0.125f);
    float co  = __expf((mo    - mn2) * 0.125f);
    float inv = 1.0f / (cs * l_run + co * lo_);

    float* cmb = (float*)ktv;                     // [2][64][33] f32, reuses tile LDS
    if (hh == 0) {
        #pragma unroll
        for (int j = 0; j < 16; j++) {
            int d0 = (j & 3) + 8 * (j >> 2) + 4 * hi;
            cmb[wp * 2112 + d0 * 33 + l31]        = cs * acc0[j];
            cmb[wp * 2112 + (d0 + 32) * 33 + l31] = cs * acc1[j];
        }
    }
    __syncthreads();
    if (hh == 1) {
        #pragma unroll
        for (int j = 0; j < 16; j++) {
            int d0 = (j & 3) + 8 * (j >> 2) + 4 * hi;
            int i0 = wp * 2112 + d0 * 33 + l31;
            int i1 = wp * 2112 + (d0 + 32) * 33 + l31;
            cmb[i0] = (cmb[i0] + cs * acc0[j]) * inv;
            cmb[i1] = (cmb[i1] + cs * acc1[j]) * inv;
        }
    }
    __syncthreads();
    // cooperative coalesced bf16 store
    #pragma unroll
    for (int p2 = 0; p2 < 2; p2++) {
        int f = p2 * 256 + tid;
        int q = f >> 3, dc = f & 7;
        int wpp = q >> 5, ql = q & 31;
        bfrag ov;
        #pragma unroll
        for (int j2 = 0; j2 < 8; j2++)
            ov[j2] = (short)f2bf(cmb[wpp * 2112 + (dc * 8 + j2) * 33 + ql]);
        *(uint4*)(Ob + (size_t)(brow + q) * INNER_ + hoff + dc * 8) = __builtin_bit_cast(uint4, ov);
    }
}

// ---------------- out = transpose(O2) + hidden ----------------
__global__ void k_out(const float* __restrict__ O2, const float* __restrict__ hid,
                      float* __restrict__ out) {
    __shared__ float t[32][33];
    int b  = blockIdx.z;
    int s0 = blockIdx.x * 32, c0 = blockIdx.y * 32;
    int tx = threadIdx.x, ty = threadIdx.y;
    t[ty][tx] = O2[(size_t)(b * S_ + s0 + ty) * C_ + c0 + tx];
    __syncthreads();
    size_t o = ((size_t)b * C_ + c0 + ty) * S_ + s0 + tx;
    out[o] = t[tx][ty] + hid[o];
}

extern "C" void kernel_launch(void* const* d_in, const int* in_sizes, int n_in,
                              void* d_out, int out_size, void* d_ws, size_t ws_size,
                              hipStream_t stream) {
    const float* hid  = (const float*)d_in[0];
    const float* Wq   = (const float*)d_in[1];
    const float* Wk   = (const float*)d_in[2];
    const float* Wv   = (const float*)d_in[3];
    const float* Wout = (const float*)d_in[4];
    const float* bout = (const float*)d_in[5];
    float* out = (float*)d_out;

    const int M = B_ * S_;   // 4096
    char* w = (char*)d_ws;
    ushort* X    = (ushort*)w;                    w += (size_t)M * QKC_ * 2;
    ushort* Qb   = (ushort*)w;                    w += (size_t)M * INNER_ * 2;
    ushort* Kbb  = (ushort*)w;                    w += (size_t)M * INNER_ * 2;
    ushort* Vtg  = (ushort*)w;                    w += (size_t)M * INNER_ * 2;   // [B*512][2048]
    ushort* Ob   = (ushort*)w;                    w += (size_t)M * INNER_ * 2;
    float*  O2   = (float*)w;                     w += (size_t)M * C_ * 4;
    ushort* Wqt  = (ushort*)w;                    w += (size_t)INNER_ * QKC_ * 2;
    ushort* Wkt  = (ushort*)w;                    w += (size_t)INNER_ * QKC_ * 2;
    ushort* Wvt  = (ushort*)w;                    w += (size_t)INNER_ * C_ * 2;
    ushort* Wot  = (ushort*)w;                    w += (size_t)C_ * INNER_ * 2;

    k_wtrans<<<dim3(QKC_ / 32, INNER_ / 32), dim3(32, 32), 0, stream>>>(Wq, Wqt, QKC_, INNER_);
    k_wtrans<<<dim3(QKC_ / 32, INNER_ / 32), dim3(32, 32), 0, stream>>>(Wk, Wkt, QKC_, INNER_);
    k_wtrans<<<dim3(C_ / 32, INNER_ / 32), dim3(32, 32), 0, stream>>>(Wv, Wvt, C_, INNER_);
    k_wtrans<<<dim3(INNER_ / 32, C_ / 32), dim3(32, 32), 0, stream>>>(Wout, Wot, INNER_, C_);

    k_transpose_in<<<dim3(S_ / 32, C_ / 32, B_), dim3(32, 32), 0, stream>>>(hid, X);
    k_emb<<<(B_ * S_ * 64) / 256, 256, 0, stream>>>(X);

    k_gemm<0><<<dim3(INNER_ / 64, M / 128), 256, 0, stream>>>(X, QKC_, Wqt, nullptr, Qb,  M, INNER_, QKC_);
    k_gemm<0><<<dim3(INNER_ / 64, M / 128), 256, 0, stream>>>(X, QKC_, Wkt, nullptr, Kbb, M, INNER_, QKC_);
    k_gemm<1><<<dim3(INNER_ / 64, M / 128), 256, 0, stream>>>(X, QKC_, Wvt, nullptr, Vtg, M, INNER_, C_);

    k_attn<<<dim3(S_ / 64, NH_, B_), 256, 0, stream>>>(Qb, Kbb, Vtg, Ob);

    k_gemm<2><<<dim3(C_ / 64, M / 128), 256, 0, stream>>>(Ob, INNER_, Wot, bout, O2, M, C_, INNER_);

    k_out<<<dim3(S_ / 32, C_ / 32, B_), dim3(32, 32), 0, stream>>>(O2, hid, out);
}

// Round 4
// 101.530 us; speedup vs baseline: 8.8447x; 1.4642x over previous
//
#include <hip/hip_runtime.h>
#include <math.h>

#define B_    2
#define C_    512
#define H_    64
#define W_    32
#define S_    2048
#define QKC_  576
#define INNER_ 512
#define NH_   8
#define HD_   64
#define TWO_PI_ 6.283185307179586f

typedef __attribute__((ext_vector_type(8))) short bfrag;
typedef __attribute__((ext_vector_type(4))) float ffrag;
typedef __attribute__((ext_vector_type(16))) float f16v;

typedef __attribute__((address_space(1))) const unsigned int as1_u32;
typedef __attribute__((address_space(3))) unsigned int as3_u32;

__device__ __forceinline__ ushort f2bf(float f) {
    unsigned u = __builtin_bit_cast(unsigned, f);
    unsigned r = (u + 0x7FFFu + ((u >> 16) & 1u)) >> 16;
    return (ushort)r;
}

__device__ __forceinline__ f16v zero16() {
    f16v z;
    #pragma unroll
    for (int i = 0; i < 16; i++) z[i] = 0.f;
    return z;
}

// ---------------- X[:, 0:512] = transpose(hidden) as bf16 ----------------
__global__ void k_transpose_in(const float* __restrict__ hid, ushort* __restrict__ X) {
    __shared__ float t[32][33];
    int b  = blockIdx.z;
    int s0 = blockIdx.x * 32, c0 = blockIdx.y * 32;
    int tx = threadIdx.x, ty = threadIdx.y;
    t[ty][tx] = hid[((size_t)b * C_ + (c0 + ty)) * S_ + s0 + tx];
    __syncthreads();
    X[((size_t)(b * S_ + s0 + ty)) * QKC_ + c0 + tx] = f2bf(t[tx][ty]);
}

// ---------------- X[:, 512:576] = embeddings (bf16) ----------------
__global__ void k_emb(ushort* __restrict__ X) {
    int idx = blockIdx.x * blockDim.x + threadIdx.x;
    if (idx >= B_ * S_ * 64) return;
    int c = idx & 63;
    int s = (idx >> 6) & (S_ - 1);
    int b = idx >> 17;
    int h = s >> 5;
    int w = s & 31;
    float val;
    if (c < 32) {
        int f = c >> 1;
        int n = h * 16 + f;
        float lx = (n == 0) ? -2.0f : log2f((float)n);
        float arg = lx * (float)(f + 1);
        val = (c & 1) ? sinf(arg) : cosf(arg);
    } else {
        int t = (c - 32) >> 1;
        float theta = ((float)t + 0.5f) * (float)(w * 16 + t) * (TWO_PI_ / 512.0f);
        val = (c & 1) ? sinf(theta) : cosf(theta);
    }
    X[(size_t)(b * S_ + s) * QKC_ + 512 + c] = f2bf(val);
}

// ---------------- W [K][N] fp32 -> Wt [N][K] bf16 ----------------
__global__ void k_wtrans(const float* __restrict__ W, ushort* __restrict__ Wt, int K, int N) {
    __shared__ float t[32][33];
    int k0 = blockIdx.x * 32, n0 = blockIdx.y * 32;
    int tx = threadIdx.x, ty = threadIdx.y;
    t[ty][tx] = W[(size_t)(k0 + ty) * N + n0 + tx];
    __syncthreads();
    Wt[(size_t)(n0 + ty) * K + k0 + tx] = f2bf(t[tx][ty]);
}

// ---------------- bf16 MFMA GEMM (unchanged) ----------------
template<int MODE>
__global__ __launch_bounds__(256) void k_gemm(const ushort* __restrict__ A, int lda,
                                              const ushort* __restrict__ Bt,
                                              const float* __restrict__ bias,
                                              void* __restrict__ Cout,
                                              int M, int N, int K) {
    __shared__ ushort smem[128 * 72 + 64 * 72];
    ushort (*As)[72] = (ushort(*)[72])smem;
    ushort (*Bs)[72] = (ushort(*)[72])(smem + 128 * 72);

    int tid = threadIdx.x;
    int l   = tid & 63;
    int wv  = tid >> 6;
    int wr  = wv >> 1, wc = wv & 1;
    int n0 = blockIdx.x * 64, m0 = blockIdx.y * 128;
    int l15 = l & 15, lg = l >> 4;

    ffrag acc[4][2];
    #pragma unroll
    for (int i = 0; i < 4; i++)
        #pragma unroll
        for (int j = 0; j < 2; j++) acc[i][j] = (ffrag){0.f, 0.f, 0.f, 0.f};

    for (int k0 = 0; k0 < K; k0 += 64) {
        __syncthreads();
        #pragma unroll
        for (int p = 0; p < 4; p++) {
            int c = tid + p * 256;
            int row = c >> 3, kc = c & 7;
            uint4 v = *(const uint4*)(A + (size_t)(m0 + row) * lda + k0 + kc * 8);
            *(uint4*)&As[row][kc * 8] = v;
        }
        #pragma unroll
        for (int p = 0; p < 2; p++) {
            int c = tid + p * 256;
            int row = c >> 3, kc = c & 7;
            uint4 v = *(const uint4*)(Bt + (size_t)(n0 + row) * K + k0 + kc * 8);
            *(uint4*)&Bs[row][kc * 8] = v;
        }
        __syncthreads();
        #pragma unroll
        for (int ks = 0; ks < 2; ks++) {
            bfrag af[4], bf[2];
            #pragma unroll
            for (int mi = 0; mi < 4; mi++)
                af[mi] = *(const bfrag*)&As[wr * 64 + mi * 16 + l15][ks * 32 + lg * 8];
            #pragma unroll
            for (int nj = 0; nj < 2; nj++)
                bf[nj] = *(const bfrag*)&Bs[wc * 32 + nj * 16 + l15][ks * 32 + lg * 8];
            #pragma unroll
            for (int mi = 0; mi < 4; mi++)
                #pragma unroll
                for (int nj = 0; nj < 2; nj++)
                    acc[mi][nj] = __builtin_amdgcn_mfma_f32_16x16x32_bf16(af[mi], bf[nj], acc[mi][nj], 0, 0, 0);
        }
    }

    if (MODE == 1) {
        ushort (*Ct)[136] = (ushort(*)[136])smem;
        __syncthreads();
        #pragma unroll
        for (int mi = 0; mi < 4; mi++)
            #pragma unroll
            for (int nj = 0; nj < 2; nj++)
                #pragma unroll
                for (int r = 0; r < 4; r++)
                    Ct[wc * 32 + nj * 16 + l15][wr * 64 + mi * 16 + lg * 4 + r] = f2bf(acc[mi][nj][r]);
        __syncthreads();
        ushort* Co = (ushort*)Cout;
        int b = m0 >> 11, s0 = m0 & 2047;
        #pragma unroll
        for (int p = 0; p < 4; p++) {
            int c = tid + p * 256;
            int rowc = c >> 4, mc = c & 15;
            uint4 v = *(uint4*)&Ct[rowc][mc * 8];
            *(uint4*)(Co + (((size_t)(b * 512 + n0 + rowc)) << 11) + s0 + mc * 8) = v;
        }
    } else {
        #pragma unroll
        for (int mi = 0; mi < 4; mi++)
            #pragma unroll
            for (int nj = 0; nj < 2; nj++)
                #pragma unroll
                for (int r = 0; r < 4; r++) {
                    int row = m0 + wr * 64 + mi * 16 + lg * 4 + r;
                    int col = n0 + wc * 32 + nj * 16 + l15;
                    if (MODE == 0)
                        ((ushort*)Cout)[(size_t)row * N + col] = f2bf(acc[mi][nj][r]);
                    else
                        ((float*)Cout)[(size_t)row * N + col] = acc[mi][nj][r] + bias[col];
                }
    }
}

// ---------------- flash attention: global_load_lds 2-phase pipeline ----------------
// grid (32 qb, 8 h, 2 b); 256 thr = 4 waves. Wave w: q-sub wp=w>>1 (32 rows), KV-half hh=w&1.
// Wave w stages LDS tile T=w (0:K h0, 1:VT h0, 2:K h1, 3:VT h1) via 8x global_load_lds(16B).
// LDS dest linear; global source inverse-XOR-swizzled (chunk ^= l>>3 == row&7); reads swizzled.
#define CVTPK(dst, a, b) asm("v_cvt_pk_bf16_f32 %0, %1, %2" : "=v"(dst) : "v"(a), "v"(b))
#define SWAP32(a, b)     asm("v_permlane32_swap_b32 %0, %1" : "+v"(a), "+v"(b))

#define GLD(gp_, lp_) __builtin_amdgcn_global_load_lds((as1_u32*)(gp_), (as3_u32*)(lp_), 16, 0, 0)

#define STAGE(buf_, kt_) {                                                    \
    const ushort* g_ = gsrc + (size_t)(kt_) * ktstride;                       \
    ushort* lp_ = ktv + (buf_) * 16384 + wv * 4096;                           \
    _Pragma("unroll")                                                         \
    for (int i_ = 0; i_ < 8; i_++)                                            \
        GLD(g_ + (size_t)i_ * istride, lp_ + i_ * 512); }

__global__ __launch_bounds__(256, 2) void k_attn(const ushort* __restrict__ Qf,
                                                 const ushort* __restrict__ Kf,
                                                 const ushort* __restrict__ Vtg,
                                                 ushort* __restrict__ Ob) {
    __shared__ ushort __attribute__((aligned(16))) ktv[2 * 4 * 4096];   // 64 KB
    __shared__ float mlsh[2][2][2][32];

    const int qb = blockIdx.x, hd = blockIdx.y, b = blockIdx.z;
    const int tid = threadIdx.x;
    const int l = tid & 63, wv = tid >> 6;
    const int wp = wv >> 1, hh = wv & 1;
    const int l31 = l & 31, hi = l >> 5, swz = l31 & 7;
    const int hoff = hd * HD_;
    const int brow = b * S_ + qb * 64;

    // Q fragments hoisted to registers (B-operand: lane holds q=l31, d-slice hi*8)
    bfrag qf[4];
    {
        const ushort* qp = Qf + (size_t)(brow + wp * 32 + l31) * INNER_ + hoff + hi * 8;
        #pragma unroll
        for (int ks = 0; ks < 4; ks++) qf[ks] = *(const bfrag*)(qp + ks * 16);
    }

    // per-wave staging source for tile T=wv: row r = i*8 + (l>>3), phys chunk l&7,
    // logical chunk = (l&7) ^ (l>>3)   [since r&7 == l>>3]
    const int hv = wv >> 1, isV = wv & 1;
    const int rr = l >> 3;
    const int clog = (l & 7) ^ rr;
    const ushort* gsrc;
    size_t istride, ktstride;
    if (isV) {
        gsrc = Vtg + (size_t)(b * 512 + hoff + rr) * 2048 + hv * 1024 + clog * 8;
        istride = (size_t)8 * 2048;
        ktstride = 64;
    } else {
        gsrc = Kf + (size_t)(b * S_ + hv * 1024 + rr) * INNER_ + hoff + clog * 8;
        istride = (size_t)8 * INNER_;
        ktstride = (size_t)64 * INNER_;
    }

    STAGE(0, 0);

    float m_run = -INFINITY, l_run = 0.f;
    f16v acc0 = zero16(), acc1 = zero16();
    int cur = 0;

    for (int kt = 0; kt < 16; kt++) {
        __syncthreads();                       // drains vmcnt: tile(cur) landed; prev reads of cur^1 done
        if (kt < 15) STAGE(cur ^ 1, kt + 1);   // issue next tile early; lands by next barrier

        const ushort* Kt  = ktv + cur * 16384 + hh * 8192;
        const ushort* Vtt = Kt + 4096;

        // ---- S = K Q^T (swapped): lane holds 32 scores for q = wp*32+l31 ----
        f16v sf0 = zero16(), sf1 = zero16();
        #pragma unroll
        for (int ks = 0; ks < 4; ks++) {
            int ch = ((ks * 2 + hi) ^ swz) * 8;
            bfrag k0 = *(const bfrag*)(Kt + l31 * 64 + ch);
            bfrag k1 = *(const bfrag*)(Kt + (l31 + 32) * 64 + ch);
            sf0 = __builtin_amdgcn_mfma_f32_32x32x16_bf16(k0, qf[ks], sf0, 0, 0, 0);
            sf1 = __builtin_amdgcn_mfma_f32_32x32x16_bf16(k1, qf[ks], sf1, 0, 0, 0);
        }

        // ---- online softmax, in-register ----
        float tm = -INFINITY;
        #pragma unroll
        for (int j = 0; j < 16; j++) { tm = fmaxf(tm, sf0[j]); tm = fmaxf(tm, sf1[j]); }
        tm = fmaxf(tm, __shfl_xor(tm, 32));
        if (!__all(tm <= m_run + 64.0f)) {     // defer-max: THR=8 nats (64 raw)
            float mn = fmaxf(m_run, tm);
            float corr = __expf((m_run - mn) * 0.125f);
            l_run *= corr;
            #pragma unroll
            for (int j = 0; j < 16; j++) { acc0[j] *= corr; acc1[j] *= corr; }
            m_run = mn;
        }
        float nm8 = -m_run * 0.125f;
        float ls = 0.f;
        #pragma unroll
        for (int j = 0; j < 16; j++) { float p = __expf(fmaf(sf0[j], 0.125f, nm8)); sf0[j] = p; ls += p; }
        #pragma unroll
        for (int j = 0; j < 16; j++) { float p = __expf(fmaf(sf1[j], 0.125f, nm8)); sf1[j] = p; ls += p; }
        ls += __shfl_xor(ls, 32);
        l_run += ls;

        // ---- O^T += V^T P  (A = V^T rows d, B = P cols q; q stays lane-local) ----
        #pragma unroll
        for (int s = 0; s < 2; s++) {
            unsigned A0, B0, A1, B1;
            CVTPK(A0, sf0[s * 8 + 0], sf0[s * 8 + 1]); CVTPK(B0, sf0[s * 8 + 4], sf0[s * 8 + 5]);
            SWAP32(A0, B0);
            CVTPK(A1, sf0[s * 8 + 2], sf0[s * 8 + 3]); CVTPK(B1, sf0[s * 8 + 6], sf0[s * 8 + 7]);
            SWAP32(A1, B1);
            uint4 u; u.x = A0; u.y = A1; u.z = B0; u.w = B1;
            bfrag pa = __builtin_bit_cast(bfrag, u);
            int ch = ((s * 2 + hi) ^ swz) * 8;
            bfrag v0 = *(const bfrag*)(Vtt + l31 * 64 + ch);
            bfrag v1 = *(const bfrag*)(Vtt + (l31 + 32) * 64 + ch);
            acc0 = __builtin_amdgcn_mfma_f32_32x32x16_bf16(v0, pa, acc0, 0, 0, 0);
            acc1 = __builtin_amdgcn_mfma_f32_32x32x16_bf16(v1, pa, acc1, 0, 0, 0);
        }
        #pragma unroll
        for (int s = 0; s < 2; s++) {
            unsigned A0, B0, A1, B1;
            CVTPK(A0, sf1[s * 8 + 0], sf1[s * 8 + 1]); CVTPK(B0, sf1[s * 8 + 4], sf1[s * 8 + 5]);
            SWAP32(A0, B0);
            CVTPK(A1, sf1[s * 8 + 2], sf1[s * 8 + 3]); CVTPK(B1, sf1[s * 8 + 6], sf1[s * 8 + 7]);
            SWAP32(A1, B1);
            uint4 u; u.x = A0; u.y = A1; u.z = B0; u.w = B1;
            bfrag pa = __builtin_bit_cast(bfrag, u);
            int ch = (((2 + s) * 2 + hi) ^ swz) * 8;
            bfrag v0 = *(const bfrag*)(Vtt + l31 * 64 + ch);
            bfrag v1 = *(const bfrag*)(Vtt + (l31 + 32) * 64 + ch);
            acc0 = __builtin_amdgcn_mfma_f32_32x32x16_bf16(v0, pa, acc0, 0, 0, 0);
            acc1 = __builtin_amdgcn_mfma_f32_32x32x16_bf16(v1, pa, acc1, 0, 0, 0);
        }

        cur ^= 1;
    }

    // ---- combine the two KV-half partials per warp-pair, via LDS ----
    if (l < 32) { mlsh[wp][hh][0][l] = m_run; mlsh[wp][hh][1][l] = l_run; }
    __syncthreads();
    float mo  = mlsh[wp][hh ^ 1][0][l31];
    float lo_ = mlsh[wp][hh ^ 1][1][l31];
    float mn2 = fmaxf(m_run, mo);
    float cs  = __expf((m_run - mn2) * 0.125f);
    float co  = __expf((mo    - mn2) * 0.125f);
    float inv = 1.0f / (cs * l_run + co * lo_);

    float* cmb = (float*)ktv;                     // [2][64][33] f32, reuses tile LDS
    if (hh == 0) {
        #pragma unroll
        for (int j = 0; j < 16; j++) {
            int d0 = (j & 3) + 8 * (j >> 2) + 4 * hi;
            cmb[wp * 2112 + d0 * 33 + l31]        = cs * acc0[j];
            cmb[wp * 2112 + (d0 + 32) * 33 + l31] = cs * acc1[j];
        }
    }
    __syncthreads();
    if (hh == 1) {
        #pragma unroll
        for (int j = 0; j < 16; j++) {
            int d0 = (j & 3) + 8 * (j >> 2) + 4 * hi;
            int i0 = wp * 2112 + d0 * 33 + l31;
            int i1 = wp * 2112 + (d0 + 32) * 33 + l31;
            cmb[i0] = (cmb[i0] + cs * acc0[j]) * inv;
            cmb[i1] = (cmb[i1] + cs * acc1[j]) * inv;
        }
    }
    __syncthreads();
    #pragma unroll
    for (int p2 = 0; p2 < 2; p2++) {
        int f = p2 * 256 + tid;
        int q = f >> 3, dc = f & 7;
        int wpp = q >> 5, ql = q & 31;
        bfrag ov;
        #pragma unroll
        for (int j2 = 0; j2 < 8; j2++)
            ov[j2] = (short)f2bf(cmb[wpp * 2112 + (dc * 8 + j2) * 33 + ql]);
        *(uint4*)(Ob + (size_t)(brow + q) * INNER_ + hoff + dc * 8) = __builtin_bit_cast(uint4, ov);
    }
}

// ---------------- out = transpose(O2) + hidden ----------------
__global__ void k_out(const float* __restrict__ O2, const float* __restrict__ hid,
                      float* __restrict__ out) {
    __shared__ float t[32][33];
    int b  = blockIdx.z;
    int s0 = blockIdx.x * 32, c0 = blockIdx.y * 32;
    int tx = threadIdx.x, ty = threadIdx.y;
    t[ty][tx] = O2[(size_t)(b * S_ + s0 + ty) * C_ + c0 + tx];
    __syncthreads();
    size_t o = ((size_t)b * C_ + c0 + ty) * S_ + s0 + tx;
    out[o] = t[tx][ty] + hid[o];
}

extern "C" void kernel_launch(void* const* d_in, const int* in_sizes, int n_in,
                              void* d_out, int out_size, void* d_ws, size_t ws_size,
                              hipStream_t stream) {
    const float* hid  = (const float*)d_in[0];
    const float* Wq   = (const float*)d_in[1];
    const float* Wk   = (const float*)d_in[2];
    const float* Wv   = (const float*)d_in[3];
    const float* Wout = (const float*)d_in[4];
    const float* bout = (const float*)d_in[5];
    float* out = (float*)d_out;

    const int M = B_ * S_;   // 4096
    char* w = (char*)d_ws;
    ushort* X    = (ushort*)w;                    w += (size_t)M * QKC_ * 2;
    ushort* Qb   = (ushort*)w;                    w += (size_t)M * INNER_ * 2;
    ushort* Kbb  = (ushort*)w;                    w += (size_t)M * INNER_ * 2;
    ushort* Vtg  = (ushort*)w;                    w += (size_t)M * INNER_ * 2;   // [B*512][2048]
    ushort* Ob   = (ushort*)w;                    w += (size_t)M * INNER_ * 2;
    float*  O2   = (float*)w;                     w += (size_t)M * C_ * 4;
    ushort* Wqt  = (ushort*)w;                    w += (size_t)INNER_ * QKC_ * 2;
    ushort* Wkt  = (ushort*)w;                    w += (size_t)INNER_ * QKC_ * 2;
    ushort* Wvt  = (ushort*)w;                    w += (size_t)INNER_ * C_ * 2;
    ushort* Wot  = (ushort*)w;                    w += (size_t)C_ * INNER_ * 2;

    k_wtrans<<<dim3(QKC_ / 32, INNER_ / 32), dim3(32, 32), 0, stream>>>(Wq, Wqt, QKC_, INNER_);
    k_wtrans<<<dim3(QKC_ / 32, INNER_ / 32), dim3(32, 32), 0, stream>>>(Wk, Wkt, QKC_, INNER_);
    k_wtrans<<<dim3(C_ / 32, INNER_ / 32), dim3(32, 32), 0, stream>>>(Wv, Wvt, C_, INNER_);
    k_wtrans<<<dim3(INNER_ / 32, C_ / 32), dim3(32, 32), 0, stream>>>(Wout, Wot, INNER_, C_);

    k_transpose_in<<<dim3(S_ / 32, C_ / 32, B_), dim3(32, 32), 0, stream>>>(hid, X);
    k_emb<<<(B_ * S_ * 64) / 256, 256, 0, stream>>>(X);

    k_gemm<0><<<dim3(INNER_ / 64, M / 128), 256, 0, stream>>>(X, QKC_, Wqt, nullptr, Qb,  M, INNER_, QKC_);
    k_gemm<0><<<dim3(INNER_ / 64, M / 128), 256, 0, stream>>>(X, QKC_, Wkt, nullptr, Kbb, M, INNER_, QKC_);
    k_gemm<1><<<dim3(INNER_ / 64, M / 128), 256, 0, stream>>>(X, QKC_, Wvt, nullptr, Vtg, M, INNER_, C_);

    k_attn<<<dim3(S_ / 64, NH_, B_), 256, 0, stream>>>(Qb, Kbb, Vtg, Ob);

    k_gemm<2><<<dim3(C_ / 64, M / 128), 256, 0, stream>>>(Ob, INNER_, Wot, bout, O2, M, C_, INNER_);

    k_out<<<dim3(S_ / 32, C_ / 32, B_), dim3(32, 32), 0, stream>>>(O2, hid, out);
}

// Round 5
// 68.253 us; speedup vs baseline: 13.1569x; 1.4875x over previous
//
#include <hip/hip_runtime.h>
#include <math.h>

#define B_    2
#define C_    512
#define H_    64
#define W_    32
#define S_    2048
#define QKC_  576
#define INNER_ 512
#define NH_   8
#define HD_   64
#define TWO_PI_ 6.283185307179586f

typedef __attribute__((ext_vector_type(8))) short bfrag;
typedef __attribute__((ext_vector_type(4))) float ffrag;
typedef __attribute__((ext_vector_type(16))) float f16v;

typedef __attribute__((address_space(1))) const unsigned int as1_u32;
typedef __attribute__((address_space(3))) unsigned int as3_u32;

__device__ __forceinline__ ushort f2bf(float f) {
    unsigned u = __builtin_bit_cast(unsigned, f);
    unsigned r = (u + 0x7FFFu + ((u >> 16) & 1u)) >> 16;
    return (ushort)r;
}

__device__ __forceinline__ f16v zero16() {
    f16v z;
    #pragma unroll
    for (int i = 0; i < 16; i++) z[i] = 0.f;
    return z;
}

#define GLD(gp_, lp_) __builtin_amdgcn_global_load_lds((as1_u32*)(gp_), (as3_u32*)(lp_), 16, 0, 0)

// ---------------- X[:,0:512] = transpose(hidden); X[:,512:576] = embeddings ----------------
__global__ void k_trans_emb(const float* __restrict__ hid, ushort* __restrict__ X) {
    __shared__ float t[32][33];
    int b  = blockIdx.z;
    int s0 = blockIdx.x * 32, c0 = blockIdx.y * 32;
    int tx = threadIdx.x, ty = threadIdx.y;
    if (c0 < 512) {
        t[ty][tx] = hid[((size_t)b * C_ + (c0 + ty)) * S_ + s0 + tx];
        __syncthreads();
        X[((size_t)(b * S_ + s0 + ty)) * QKC_ + c0 + tx] = f2bf(t[tx][ty]);
    } else {
        int c = c0 - 512 + tx;
        int s = s0 + ty;
        int h = s >> 5, w = s & 31;
        float val;
        if (c < 32) {
            int f = c >> 1;
            int n = h * 16 + f;
            float lx = (n == 0) ? -2.0f : log2f((float)n);
            float arg = lx * (float)(f + 1);
            val = (c & 1) ? sinf(arg) : cosf(arg);
        } else {
            int tt = (c - 32) >> 1;
            float theta = ((float)tt + 0.5f) * (float)(w * 16 + tt) * (TWO_PI_ / 512.0f);
            val = (c & 1) ? sinf(theta) : cosf(theta);
        }
        X[(size_t)(b * S_ + s) * QKC_ + c0 + tx] = f2bf(val);
    }
}

// ---------------- all 4 weight transposes in one launch ----------------
__global__ void k_wtrans_all(const float* __restrict__ Wq, const float* __restrict__ Wk,
                             const float* __restrict__ Wv, const float* __restrict__ Wo,
                             ushort* __restrict__ Wqt, ushort* __restrict__ Wkt,
                             ushort* __restrict__ Wvt, ushort* __restrict__ Wot) {
    __shared__ float t[32][33];
    int z = blockIdx.z;
    const float* W; ushort* Wt; int K;
    if (z == 0)      { W = Wq; Wt = Wqt; K = QKC_; }
    else if (z == 1) { W = Wk; Wt = Wkt; K = QKC_; }
    else if (z == 2) { W = Wv; Wt = Wvt; K = C_; }
    else             { W = Wo; Wt = Wot; K = INNER_; }
    int k0 = blockIdx.x * 32, n0 = blockIdx.y * 32;
    if (k0 >= K) return;
    int tx = threadIdx.x, ty = threadIdx.y;
    t[ty][tx] = W[(size_t)(k0 + ty) * 512 + n0 + tx];
    __syncthreads();
    Wt[(size_t)(n0 + ty) * K + k0 + tx] = f2bf(t[tx][ty]);
}

// ---------------- fused QKV GEMM, global_load_lds 2-phase pipeline ----------------
// grid (24, 32): n0 = bx*64 over [Q|K|V] x 512; m0 = by*128. 256 thr = 4 waves (2x2).
// LDS: dbuf x (A 128x64 + B 64x64) bf16, both-sides XOR-swizzled, 48 KB.
#define GSTAGE(buf_, k0_) {                                                   \
    _Pragma("unroll")                                                         \
    for (int i_ = 0; i_ < 6; i_++)                                            \
        GLD(gp[i_] + (k0_), tl + (buf_) * 12288 + lo[i_]); }

__global__ __launch_bounds__(256, 3) void k_qkv(const ushort* __restrict__ X,
                                                const ushort* __restrict__ Wqt,
                                                const ushort* __restrict__ Wkt,
                                                const ushort* __restrict__ Wvt,
                                                ushort* __restrict__ Qb,
                                                ushort* __restrict__ Kbb,
                                                ushort* __restrict__ Vtg) {
    __shared__ ushort __attribute__((aligned(16))) tl[2 * 12288];   // 48 KB

    int tid = threadIdx.x;
    int l = tid & 63, wv = tid >> 6;
    int wr = wv >> 1, wc = wv & 1;
    int n0 = blockIdx.x * 64, m0 = blockIdx.y * 128;
    int sel = n0 >> 9, n0l = n0 & 511;
    const ushort* Bt = (sel == 0) ? Wqt : (sel == 1) ? Wkt : Wvt;
    const int K = (sel < 2) ? QKC_ : C_;
    const int nst = K >> 6;
    int l15 = l & 15, lg = l >> 4;
    int swz = l15 & 7;

    // staging sources: 24 chunks of 1KB (0..15 = A rows, 16..23 = B rows); 6 per wave
    const ushort* gp[6];
    unsigned lo[6];
    {
        int rsub = l >> 3;
        int clog = (l & 7) ^ rsub;   // inverse-swizzled global column chunk
        #pragma unroll
        for (int i = 0; i < 6; i++) {
            int c = wv * 6 + i;
            lo[i] = c * 512;
            if (c < 16) gp[i] = X  + (size_t)(m0  + c * 8        + rsub) * QKC_ + clog * 8;
            else        gp[i] = Bt + (size_t)(n0l + (c - 16) * 8 + rsub) * K    + clog * 8;
        }
    }

    ffrag acc[4][2];
    #pragma unroll
    for (int i = 0; i < 4; i++)
        #pragma unroll
        for (int j = 0; j < 2; j++) acc[i][j] = (ffrag){0.f, 0.f, 0.f, 0.f};

    GSTAGE(0, 0);
    int cur = 0;
    for (int kt = 0; kt < nst; kt++) {
        __syncthreads();                          // drains vmcnt: tile(cur) landed
        if (kt + 1 < nst) GSTAGE(cur ^ 1, (kt + 1) * 64);
        const ushort* As = tl + cur * 12288;
        const ushort* Bs = As + 8192;
        #pragma unroll
        for (int ks = 0; ks < 2; ks++) {
            int cl = ks * 4 + lg;
            int ch = (cl ^ swz) * 8;
            bfrag af[4], bf[2];
            #pragma unroll
            for (int mi = 0; mi < 4; mi++)
                af[mi] = *(const bfrag*)(As + (wr * 64 + mi * 16 + l15) * 64 + ch);
            #pragma unroll
            for (int nj = 0; nj < 2; nj++)
                bf[nj] = *(const bfrag*)(Bs + (wc * 32 + nj * 16 + l15) * 64 + ch);
            #pragma unroll
            for (int mi = 0; mi < 4; mi++)
                #pragma unroll
                for (int nj = 0; nj < 2; nj++)
                    acc[mi][nj] = __builtin_amdgcn_mfma_f32_16x16x32_bf16(af[mi], bf[nj], acc[mi][nj], 0, 0, 0);
        }
        cur ^= 1;
    }

    if (sel < 2) {
        ushort* Co = sel ? Kbb : Qb;
        #pragma unroll
        for (int mi = 0; mi < 4; mi++)
            #pragma unroll
            for (int nj = 0; nj < 2; nj++)
                #pragma unroll
                for (int r = 0; r < 4; r++) {
                    int row = m0 + wr * 64 + mi * 16 + lg * 4 + r;
                    int col = n0l + wc * 32 + nj * 16 + l15;
                    Co[(size_t)row * INNER_ + col] = f2bf(acc[mi][nj][r]);
                }
    } else {
        // V: transpose epilogue -> Vtg[(b*512 + n)][2048]
        ushort (*Ct)[136] = (ushort(*)[136])tl;
        __syncthreads();
        #pragma unroll
        for (int mi = 0; mi < 4; mi++)
            #pragma unroll
            for (int nj = 0; nj < 2; nj++)
                #pragma unroll
                for (int r = 0; r < 4; r++)
                    Ct[wc * 32 + nj * 16 + l15][wr * 64 + mi * 16 + lg * 4 + r] = f2bf(acc[mi][nj][r]);
        __syncthreads();
        int b = m0 >> 11, s0m = m0 & 2047;
        #pragma unroll
        for (int p = 0; p < 4; p++) {
            int c = tid + p * 256;
            int rowc = c >> 4, mc = c & 15;
            uint4 v = *(uint4*)&Ct[rowc][mc * 8];
            *(uint4*)(Vtg + (((size_t)(b * 512 + n0l + rowc)) << 11) + s0m + mc * 8) = v;
        }
    }
}

// ---------------- output GEMM + bias + transpose + residual, fp32 out ----------------
__global__ __launch_bounds__(256, 2) void k_og(const ushort* __restrict__ Ob,
                                               const ushort* __restrict__ Wot,
                                               const float* __restrict__ bias,
                                               const float* __restrict__ hid,
                                               float* __restrict__ out) {
    __shared__ ushort __attribute__((aligned(16))) tl[2 * 12288];

    int tid = threadIdx.x;
    int l = tid & 63, wv = tid >> 6;
    int wr = wv >> 1, wc = wv & 1;
    int n0 = blockIdx.x * 64, m0 = blockIdx.y * 128;
    int l15 = l & 15, lg = l >> 4;
    int swz = l15 & 7;

    const ushort* gp[6];
    unsigned lo[6];
    {
        int rsub = l >> 3;
        int clog = (l & 7) ^ rsub;
        #pragma unroll
        for (int i = 0; i < 6; i++) {
            int c = wv * 6 + i;
            lo[i] = c * 512;
            if (c < 16) gp[i] = Ob  + (size_t)(m0 + c * 8        + rsub) * INNER_ + clog * 8;
            else        gp[i] = Wot + (size_t)(n0 + (c - 16) * 8 + rsub) * INNER_ + clog * 8;
        }
    }

    ffrag acc[4][2];
    #pragma unroll
    for (int i = 0; i < 4; i++)
        #pragma unroll
        for (int j = 0; j < 2; j++) acc[i][j] = (ffrag){0.f, 0.f, 0.f, 0.f};

    GSTAGE(0, 0);
    int cur = 0;
    for (int kt = 0; kt < 8; kt++) {
        __syncthreads();
        if (kt < 7) GSTAGE(cur ^ 1, (kt + 1) * 64);
        const ushort* As = tl + cur * 12288;
        const ushort* Bs = As + 8192;
        #pragma unroll
        for (int ks = 0; ks < 2; ks++) {
            int cl = ks * 4 + lg;
            int ch = (cl ^ swz) * 8;
            bfrag af[4], bf[2];
            #pragma unroll
            for (int mi = 0; mi < 4; mi++)
                af[mi] = *(const bfrag*)(As + (wr * 64 + mi * 16 + l15) * 64 + ch);
            #pragma unroll
            for (int nj = 0; nj < 2; nj++)
                bf[nj] = *(const bfrag*)(Bs + (wc * 32 + nj * 16 + l15) * 64 + ch);
            #pragma unroll
            for (int mi = 0; mi < 4; mi++)
                #pragma unroll
                for (int nj = 0; nj < 2; nj++)
                    acc[mi][nj] = __builtin_amdgcn_mfma_f32_16x16x32_bf16(af[mi], bf[nj], acc[mi][nj], 0, 0, 0);
        }
        cur ^= 1;
    }

    // epilogue: Cf[c][m] = acc + bias; then out[(b*512+c)][s] = Cf + hid
    float (*Cf)[129] = (float(*)[129])tl;
    float bv[2];
    #pragma unroll
    for (int nj = 0; nj < 2; nj++) bv[nj] = bias[n0 + wc * 32 + nj * 16 + l15];
    __syncthreads();
    #pragma unroll
    for (int mi = 0; mi < 4; mi++)
        #pragma unroll
        for (int nj = 0; nj < 2; nj++)
            #pragma unroll
            for (int r = 0; r < 4; r++)
                Cf[wc * 32 + nj * 16 + l15][wr * 64 + mi * 16 + lg * 4 + r] = acc[mi][nj][r] + bv[nj];
    __syncthreads();
    int b = m0 >> 11, s0m = m0 & 2047;
    #pragma unroll
    for (int p = 0; p < 8; p++) {
        int f = p * 256 + tid;
        int c = f >> 5, sq = (f & 31) * 4;
        size_t o = (((size_t)(b * 512 + n0 + c)) << 11) + s0m + sq;
        float4 hv = *(const float4*)(hid + o);
        float4 cv = *(float4*)&Cf[c][sq];
        cv.x += hv.x; cv.y += hv.y; cv.z += hv.z; cv.w += hv.w;
        *(float4*)(out + o) = cv;
    }
}

// ---------------- flash attention (unchanged from round 4) ----------------
#define CVTPK(dst, a, b) asm("v_cvt_pk_bf16_f32 %0, %1, %2" : "=v"(dst) : "v"(a), "v"(b))
#define SWAP32(a, b)     asm("v_permlane32_swap_b32 %0, %1" : "+v"(a), "+v"(b))

#define STAGE(buf_, kt_) {                                                    \
    const ushort* g_ = gsrc + (size_t)(kt_) * ktstride;                       \
    ushort* lp_ = ktv + (buf_) * 16384 + wv * 4096;                           \
    _Pragma("unroll")                                                         \
    for (int i_ = 0; i_ < 8; i_++)                                            \
        GLD(g_ + (size_t)i_ * istride, lp_ + i_ * 512); }

__global__ __launch_bounds__(256, 2) void k_attn(const ushort* __restrict__ Qf,
                                                 const ushort* __restrict__ Kf,
                                                 const ushort* __restrict__ Vtg,
                                                 ushort* __restrict__ Ob) {
    __shared__ ushort __attribute__((aligned(16))) ktv[2 * 4 * 4096];   // 64 KB
    __shared__ float mlsh[2][2][2][32];

    const int qb = blockIdx.x, hd = blockIdx.y, b = blockIdx.z;
    const int tid = threadIdx.x;
    const int l = tid & 63, wv = tid >> 6;
    const int wp = wv >> 1, hh = wv & 1;
    const int l31 = l & 31, hi = l >> 5, swz = l31 & 7;
    const int hoff = hd * HD_;
    const int brow = b * S_ + qb * 64;

    bfrag qf[4];
    {
        const ushort* qp = Qf + (size_t)(brow + wp * 32 + l31) * INNER_ + hoff + hi * 8;
        #pragma unroll
        for (int ks = 0; ks < 4; ks++) qf[ks] = *(const bfrag*)(qp + ks * 16);
    }

    const int hv = wv >> 1, isV = wv & 1;
    const int rr = l >> 3;
    const int clog = (l & 7) ^ rr;
    const ushort* gsrc;
    size_t istride, ktstride;
    if (isV) {
        gsrc = Vtg + (size_t)(b * 512 + hoff + rr) * 2048 + hv * 1024 + clog * 8;
        istride = (size_t)8 * 2048;
        ktstride = 64;
    } else {
        gsrc = Kf + (size_t)(b * S_ + hv * 1024 + rr) * INNER_ + hoff + clog * 8;
        istride = (size_t)8 * INNER_;
        ktstride = (size_t)64 * INNER_;
    }

    STAGE(0, 0);

    float m_run = -INFINITY, l_run = 0.f;
    f16v acc0 = zero16(), acc1 = zero16();
    int cur = 0;

    for (int kt = 0; kt < 16; kt++) {
        __syncthreads();
        if (kt < 15) STAGE(cur ^ 1, kt + 1);

        const ushort* Kt  = ktv + cur * 16384 + hh * 8192;
        const ushort* Vtt = Kt + 4096;

        f16v sf0 = zero16(), sf1 = zero16();
        #pragma unroll
        for (int ks = 0; ks < 4; ks++) {
            int ch = ((ks * 2 + hi) ^ swz) * 8;
            bfrag k0 = *(const bfrag*)(Kt + l31 * 64 + ch);
            bfrag k1 = *(const bfrag*)(Kt + (l31 + 32) * 64 + ch);
            sf0 = __builtin_amdgcn_mfma_f32_32x32x16_bf16(k0, qf[ks], sf0, 0, 0, 0);
            sf1 = __builtin_amdgcn_mfma_f32_32x32x16_bf16(k1, qf[ks], sf1, 0, 0, 0);
        }

        float tm = -INFINITY;
        #pragma unroll
        for (int j = 0; j < 16; j++) { tm = fmaxf(tm, sf0[j]); tm = fmaxf(tm, sf1[j]); }
        tm = fmaxf(tm, __shfl_xor(tm, 32));
        if (!__all(tm <= m_run + 64.0f)) {
            float mn = fmaxf(m_run, tm);
            float corr = __expf((m_run - mn) * 0.125f);
            l_run *= corr;
            #pragma unroll
            for (int j = 0; j < 16; j++) { acc0[j] *= corr; acc1[j] *= corr; }
            m_run = mn;
        }
        float nm8 = -m_run * 0.125f;
        float ls = 0.f;
        #pragma unroll
        for (int j = 0; j < 16; j++) { float p = __expf(fmaf(sf0[j], 0.125f, nm8)); sf0[j] = p; ls += p; }
        #pragma unroll
        for (int j = 0; j < 16; j++) { float p = __expf(fmaf(sf1[j], 0.125f, nm8)); sf1[j] = p; ls += p; }
        ls += __shfl_xor(ls, 32);
        l_run += ls;

        #pragma unroll
        for (int s = 0; s < 2; s++) {
            unsigned A0, B0, A1, B1;
            CVTPK(A0, sf0[s * 8 + 0], sf0[s * 8 + 1]); CVTPK(B0, sf0[s * 8 + 4], sf0[s * 8 + 5]);
            SWAP32(A0, B0);
            CVTPK(A1, sf0[s * 8 + 2], sf0[s * 8 + 3]); CVTPK(B1, sf0[s * 8 + 6], sf0[s * 8 + 7]);
            SWAP32(A1, B1);
            uint4 u; u.x = A0; u.y = A1; u.z = B0; u.w = B1;
            bfrag pa = __builtin_bit_cast(bfrag, u);
            int ch = ((s * 2 + hi) ^ swz) * 8;
            bfrag v0 = *(const bfrag*)(Vtt + l31 * 64 + ch);
            bfrag v1 = *(const bfrag*)(Vtt + (l31 + 32) * 64 + ch);
            acc0 = __builtin_amdgcn_mfma_f32_32x32x16_bf16(v0, pa, acc0, 0, 0, 0);
            acc1 = __builtin_amdgcn_mfma_f32_32x32x16_bf16(v1, pa, acc1, 0, 0, 0);
        }
        #pragma unroll
        for (int s = 0; s < 2; s++) {
            unsigned A0, B0, A1, B1;
            CVTPK(A0, sf1[s * 8 + 0], sf1[s * 8 + 1]); CVTPK(B0, sf1[s * 8 + 4], sf1[s * 8 + 5]);
            SWAP32(A0, B0);
            CVTPK(A1, sf1[s * 8 + 2], sf1[s * 8 + 3]); CVTPK(B1, sf1[s * 8 + 6], sf1[s * 8 + 7]);
            SWAP32(A1, B1);
            uint4 u; u.x = A0; u.y = A1; u.z = B0; u.w = B1;
            bfrag pa = __builtin_bit_cast(bfrag, u);
            int ch = (((2 + s) * 2 + hi) ^ swz) * 8;
            bfrag v0 = *(const bfrag*)(Vtt + l31 * 64 + ch);
            bfrag v1 = *(const bfrag*)(Vtt + (l31 + 32) * 64 + ch);
            acc0 = __builtin_amdgcn_mfma_f32_32x32x16_bf16(v0, pa, acc0, 0, 0, 0);
            acc1 = __builtin_amdgcn_mfma_f32_32x32x16_bf16(v1, pa, acc1, 0, 0, 0);
        }

        cur ^= 1;
    }

    if (l < 32) { mlsh[wp][hh][0][l] = m_run; mlsh[wp][hh][1][l] = l_run; }
    __syncthreads();
    float mo  = mlsh[wp][hh ^ 1][0][l31];
    float lo_ = mlsh[wp][hh ^ 1][1][l31];
    float mn2 = fmaxf(m_run, mo);
    float cs  = __expf((m_run - mn2) * 0.125f);
    float co  = __expf((mo    - mn2) * 0.125f);
    float inv = 1.0f / (cs * l_run + co * lo_);

    float* cmb = (float*)ktv;
    if (hh == 0) {
        #pragma unroll
        for (int j = 0; j < 16; j++) {
            int d0 = (j & 3) + 8 * (j >> 2) + 4 * hi;
            cmb[wp * 2112 + d0 * 33 + l31]        = cs * acc0[j];
            cmb[wp * 2112 + (d0 + 32) * 33 + l31] = cs * acc1[j];
        }
    }
    __syncthreads();
    if (hh == 1) {
        #pragma unroll
        for (int j = 0; j < 16; j++) {
            int d0 = (j & 3) + 8 * (j >> 2) + 4 * hi;
            int i0 = wp * 2112 + d0 * 33 + l31;
            int i1 = wp * 2112 + (d0 + 32) * 33 + l31;
            cmb[i0] = (cmb[i0] + cs * acc0[j]) * inv;
            cmb[i1] = (cmb[i1] + cs * acc1[j]) * inv;
        }
    }
    __syncthreads();
    #pragma unroll
    for (int p2 = 0; p2 < 2; p2++) {
        int f = p2 * 256 + tid;
        int q = f >> 3, dc = f & 7;
        int wpp = q >> 5, ql = q & 31;
        bfrag ov;
        #pragma unroll
        for (int j2 = 0; j2 < 8; j2++)
            ov[j2] = (short)f2bf(cmb[wpp * 2112 + (dc * 8 + j2) * 33 + ql]);
        *(uint4*)(Ob + (size_t)(brow + q) * INNER_ + hoff + dc * 8) = __builtin_bit_cast(uint4, ov);
    }
}

extern "C" void kernel_launch(void* const* d_in, const int* in_sizes, int n_in,
                              void* d_out, int out_size, void* d_ws, size_t ws_size,
                              hipStream_t stream) {
    const float* hid  = (const float*)d_in[0];
    const float* Wq   = (const float*)d_in[1];
    const float* Wk   = (const float*)d_in[2];
    const float* Wv   = (const float*)d_in[3];
    const float* Wout = (const float*)d_in[4];
    const float* bout = (const float*)d_in[5];
    float* out = (float*)d_out;

    const int M = B_ * S_;   // 4096
    char* w = (char*)d_ws;
    ushort* X    = (ushort*)w;                    w += (size_t)M * QKC_ * 2;
    ushort* Qb   = (ushort*)w;                    w += (size_t)M * INNER_ * 2;
    ushort* Kbb  = (ushort*)w;                    w += (size_t)M * INNER_ * 2;
    ushort* Vtg  = (ushort*)w;                    w += (size_t)M * INNER_ * 2;   // [B*512][2048]
    ushort* Ob   = (ushort*)w;                    w += (size_t)M * INNER_ * 2;
    ushort* Wqt  = (ushort*)w;                    w += (size_t)INNER_ * QKC_ * 2;
    ushort* Wkt  = (ushort*)w;                    w += (size_t)INNER_ * QKC_ * 2;
    ushort* Wvt  = (ushort*)w;                    w += (size_t)INNER_ * C_ * 2;
    ushort* Wot  = (ushort*)w;                    w += (size_t)C_ * INNER_ * 2;

    k_wtrans_all<<<dim3(18, 16, 4), dim3(32, 32), 0, stream>>>(Wq, Wk, Wv, Wout,
                                                               Wqt, Wkt, Wvt, Wot);
    k_trans_emb<<<dim3(S_ / 32, 18, B_), dim3(32, 32), 0, stream>>>(hid, X);

    k_qkv<<<dim3(24, M / 128), 256, 0, stream>>>(X, Wqt, Wkt, Wvt, Qb, Kbb, Vtg);

    k_attn<<<dim3(S_ / 64, NH_, B_), 256, 0, stream>>>(Qb, Kbb, Vtg, Ob);

    k_og<<<dim3(C_ / 64, M / 128), 256, 0, stream>>>(Ob, Wot, bout, hid, out);
}

// Round 6
// 65.917 us; speedup vs baseline: 13.6232x; 1.0354x over previous
//
#include <hip/hip_runtime.h>
#include <math.h>

#define B_    2
#define C_    512
#define H_    64
#define W_    32
#define S_    2048
#define QKC_  576
#define INNER_ 512
#define NH_   8
#define HD_   64
#define TWO_PI_ 6.283185307179586f

typedef __attribute__((ext_vector_type(8))) short bfrag;
typedef __attribute__((ext_vector_type(4))) float ffrag;
typedef __attribute__((ext_vector_type(16))) float f16v;

typedef __attribute__((address_space(1))) const unsigned int as1_u32;
typedef __attribute__((address_space(3))) unsigned int as3_u32;

__device__ __forceinline__ ushort f2bf(float f) {
    unsigned u = __builtin_bit_cast(unsigned, f);
    unsigned r = (u + 0x7FFFu + ((u >> 16) & 1u)) >> 16;
    return (ushort)r;
}

__device__ __forceinline__ f16v zero16() {
    f16v z;
    #pragma unroll
    for (int i = 0; i < 16; i++) z[i] = 0.f;
    return z;
}

#define GLD(gp_, lp_) __builtin_amdgcn_global_load_lds((as1_u32*)(gp_), (as3_u32*)(lp_), 16, 0, 0)
#define EXPA(dst_, x_) asm("v_exp_f32 %0, %1" : "=v"(dst_) : "v"(x_))
#define SC_LOG2E 0.18033688011f   /* 0.125 * log2(e) */

// ---------------- X[:,0:512] = transpose(hidden); X[:,512:576] = embeddings ----------------
__global__ void k_trans_emb(const float* __restrict__ hid, ushort* __restrict__ X) {
    __shared__ float t[32][33];
    int b  = blockIdx.z;
    int s0 = blockIdx.x * 32, c0 = blockIdx.y * 32;
    int tx = threadIdx.x, ty = threadIdx.y;
    if (c0 < 512) {
        t[ty][tx] = hid[((size_t)b * C_ + (c0 + ty)) * S_ + s0 + tx];
        __syncthreads();
        X[((size_t)(b * S_ + s0 + ty)) * QKC_ + c0 + tx] = f2bf(t[tx][ty]);
    } else {
        int c = c0 - 512 + tx;
        int s = s0 + ty;
        int h = s >> 5, w = s & 31;
        float val;
        if (c < 32) {
            int f = c >> 1;
            int n = h * 16 + f;
            float lx = (n == 0) ? -2.0f : log2f((float)n);
            float arg = lx * (float)(f + 1);
            val = (c & 1) ? sinf(arg) : cosf(arg);
        } else {
            int tt = (c - 32) >> 1;
            float theta = ((float)tt + 0.5f) * (float)(w * 16 + tt) * (TWO_PI_ / 512.0f);
            val = (c & 1) ? sinf(theta) : cosf(theta);
        }
        X[(size_t)(b * S_ + s) * QKC_ + c0 + tx] = f2bf(val);
    }
}

// ---------------- all 4 weight transposes in one launch ----------------
__global__ void k_wtrans_all(const float* __restrict__ Wq, const float* __restrict__ Wk,
                             const float* __restrict__ Wv, const float* __restrict__ Wo,
                             ushort* __restrict__ Wqt, ushort* __restrict__ Wkt,
                             ushort* __restrict__ Wvt, ushort* __restrict__ Wot) {
    __shared__ float t[32][33];
    int z = blockIdx.z;
    const float* W; ushort* Wt; int K;
    if (z == 0)      { W = Wq; Wt = Wqt; K = QKC_; }
    else if (z == 1) { W = Wk; Wt = Wkt; K = QKC_; }
    else if (z == 2) { W = Wv; Wt = Wvt; K = C_; }
    else             { W = Wo; Wt = Wot; K = INNER_; }
    int k0 = blockIdx.x * 32, n0 = blockIdx.y * 32;
    if (k0 >= K) return;
    int tx = threadIdx.x, ty = threadIdx.y;
    t[ty][tx] = W[(size_t)(k0 + ty) * 512 + n0 + tx];
    __syncthreads();
    Wt[(size_t)(n0 + ty) * K + k0 + tx] = f2bf(t[tx][ty]);
}

// ---------------- fused QKV GEMM, global_load_lds 2-phase pipeline, XCD-swizzled ----------------
#define GSTAGE(buf_, k0_) {                                                   \
    _Pragma("unroll")                                                         \
    for (int i_ = 0; i_ < 6; i_++)                                            \
        GLD(gp[i_] + (k0_), tl + (buf_) * 12288 + lo[i_]); }

__global__ __launch_bounds__(256, 3) void k_qkv(const ushort* __restrict__ X,
                                                const ushort* __restrict__ Wqt,
                                                const ushort* __restrict__ Wkt,
                                                const ushort* __restrict__ Wvt,
                                                ushort* __restrict__ Qb,
                                                ushort* __restrict__ Kbb,
                                                ushort* __restrict__ Vtg) {
    __shared__ ushort __attribute__((aligned(16))) tl[2 * 12288];   // 48 KB

    int tid = threadIdx.x;
    int l = tid & 63, wv = tid >> 6;
    int wr = wv >> 1, wc = wv & 1;
    // XCD-aware swizzle: 768 blocks = 8 XCDs x 96; chunk shares A-panels + weights in L2
    int bid = blockIdx.x;
    int lgc = (bid & 7) * 96 + (bid >> 3);
    int bx = lgc % 24, by = lgc / 24;
    int n0 = bx * 64, m0 = by * 128;
    int sel = n0 >> 9, n0l = n0 & 511;
    const ushort* Bt = (sel == 0) ? Wqt : (sel == 1) ? Wkt : Wvt;
    const int K = (sel < 2) ? QKC_ : C_;
    const int nst = K >> 6;
    int l15 = l & 15, lg = l >> 4;
    int swz = l15 & 7;

    const ushort* gp[6];
    unsigned lo[6];
    {
        int rsub = l >> 3;
        int clog = (l & 7) ^ rsub;   // inverse-swizzled global column chunk
        #pragma unroll
        for (int i = 0; i < 6; i++) {
            int c = wv * 6 + i;
            lo[i] = c * 512;
            if (c < 16) gp[i] = X  + (size_t)(m0  + c * 8        + rsub) * QKC_ + clog * 8;
            else        gp[i] = Bt + (size_t)(n0l + (c - 16) * 8 + rsub) * K    + clog * 8;
        }
    }

    ffrag acc[4][2];
    #pragma unroll
    for (int i = 0; i < 4; i++)
        #pragma unroll
        for (int j = 0; j < 2; j++) acc[i][j] = (ffrag){0.f, 0.f, 0.f, 0.f};

    GSTAGE(0, 0);
    int cur = 0;
    for (int kt = 0; kt < nst; kt++) {
        __syncthreads();
        if (kt + 1 < nst) GSTAGE(cur ^ 1, (kt + 1) * 64);
        const ushort* As = tl + cur * 12288;
        const ushort* Bs = As + 8192;
        #pragma unroll
        for (int ks = 0; ks < 2; ks++) {
            int cl = ks * 4 + lg;
            int ch = (cl ^ swz) * 8;
            bfrag af[4], bf[2];
            #pragma unroll
            for (int mi = 0; mi < 4; mi++)
                af[mi] = *(const bfrag*)(As + (wr * 64 + mi * 16 + l15) * 64 + ch);
            #pragma unroll
            for (int nj = 0; nj < 2; nj++)
                bf[nj] = *(const bfrag*)(Bs + (wc * 32 + nj * 16 + l15) * 64 + ch);
            #pragma unroll
            for (int mi = 0; mi < 4; mi++)
                #pragma unroll
                for (int nj = 0; nj < 2; nj++)
                    acc[mi][nj] = __builtin_amdgcn_mfma_f32_16x16x32_bf16(af[mi], bf[nj], acc[mi][nj], 0, 0, 0);
        }
        cur ^= 1;
    }

    if (sel < 2) {
        ushort* Co = sel ? Kbb : Qb;
        #pragma unroll
        for (int mi = 0; mi < 4; mi++)
            #pragma unroll
            for (int nj = 0; nj < 2; nj++)
                #pragma unroll
                for (int r = 0; r < 4; r++) {
                    int row = m0 + wr * 64 + mi * 16 + lg * 4 + r;
                    int col = n0l + wc * 32 + nj * 16 + l15;
                    Co[(size_t)row * INNER_ + col] = f2bf(acc[mi][nj][r]);
                }
    } else {
        ushort (*Ct)[136] = (ushort(*)[136])tl;
        __syncthreads();
        #pragma unroll
        for (int mi = 0; mi < 4; mi++)
            #pragma unroll
            for (int nj = 0; nj < 2; nj++)
                #pragma unroll
                for (int r = 0; r < 4; r++)
                    Ct[wc * 32 + nj * 16 + l15][wr * 64 + mi * 16 + lg * 4 + r] = f2bf(acc[mi][nj][r]);
        __syncthreads();
        int b = m0 >> 11, s0m = m0 & 2047;
        #pragma unroll
        for (int p = 0; p < 4; p++) {
            int c = tid + p * 256;
            int rowc = c >> 4, mc = c & 15;
            uint4 v = *(uint4*)&Ct[rowc][mc * 8];
            *(uint4*)(Vtg + (((size_t)(b * 512 + n0l + rowc)) << 11) + s0m + mc * 8) = v;
        }
    }
}

// ---------------- output GEMM + bias + transpose + residual, XCD-swizzled ----------------
__global__ __launch_bounds__(256, 2) void k_og(const ushort* __restrict__ Ob,
                                               const ushort* __restrict__ Wot,
                                               const float* __restrict__ bias,
                                               const float* __restrict__ hid,
                                               float* __restrict__ out) {
    __shared__ ushort __attribute__((aligned(16))) tl[2 * 12288];

    int tid = threadIdx.x;
    int l = tid & 63, wv = tid >> 6;
    int wr = wv >> 1, wc = wv & 1;
    int bid = blockIdx.x;                 // 256 blocks = 8 x 32
    int lgc = (bid & 7) * 32 + (bid >> 3);
    int bx = lgc & 7, by = lgc >> 3;
    int n0 = bx * 64, m0 = by * 128;
    int l15 = l & 15, lg = l >> 4;
    int swz = l15 & 7;

    const ushort* gp[6];
    unsigned lo[6];
    {
        int rsub = l >> 3;
        int clog = (l & 7) ^ rsub;
        #pragma unroll
        for (int i = 0; i < 6; i++) {
            int c = wv * 6 + i;
            lo[i] = c * 512;
            if (c < 16) gp[i] = Ob  + (size_t)(m0 + c * 8        + rsub) * INNER_ + clog * 8;
            else        gp[i] = Wot + (size_t)(n0 + (c - 16) * 8 + rsub) * INNER_ + clog * 8;
        }
    }

    ffrag acc[4][2];
    #pragma unroll
    for (int i = 0; i < 4; i++)
        #pragma unroll
        for (int j = 0; j < 2; j++) acc[i][j] = (ffrag){0.f, 0.f, 0.f, 0.f};

    GSTAGE(0, 0);
    int cur = 0;
    for (int kt = 0; kt < 8; kt++) {
        __syncthreads();
        if (kt < 7) GSTAGE(cur ^ 1, (kt + 1) * 64);
        const ushort* As = tl + cur * 12288;
        const ushort* Bs = As + 8192;
        #pragma unroll
        for (int ks = 0; ks < 2; ks++) {
            int cl = ks * 4 + lg;
            int ch = (cl ^ swz) * 8;
            bfrag af[4], bf[2];
            #pragma unroll
            for (int mi = 0; mi < 4; mi++)
                af[mi] = *(const bfrag*)(As + (wr * 64 + mi * 16 + l15) * 64 + ch);
            #pragma unroll
            for (int nj = 0; nj < 2; nj++)
                bf[nj] = *(const bfrag*)(Bs + (wc * 32 + nj * 16 + l15) * 64 + ch);
            #pragma unroll
            for (int mi = 0; mi < 4; mi++)
                #pragma unroll
                for (int nj = 0; nj < 2; nj++)
                    acc[mi][nj] = __builtin_amdgcn_mfma_f32_16x16x32_bf16(af[mi], bf[nj], acc[mi][nj], 0, 0, 0);
        }
        cur ^= 1;
    }

    float (*Cf)[129] = (float(*)[129])tl;
    float bv[2];
    #pragma unroll
    for (int nj = 0; nj < 2; nj++) bv[nj] = bias[n0 + wc * 32 + nj * 16 + l15];
    __syncthreads();
    #pragma unroll
    for (int mi = 0; mi < 4; mi++)
        #pragma unroll
        for (int nj = 0; nj < 2; nj++)
            #pragma unroll
            for (int r = 0; r < 4; r++)
                Cf[wc * 32 + nj * 16 + l15][wr * 64 + mi * 16 + lg * 4 + r] = acc[mi][nj][r] + bv[nj];
    __syncthreads();
    int b = m0 >> 11, s0m = m0 & 2047;
    #pragma unroll
    for (int p = 0; p < 8; p++) {
        int f = p * 256 + tid;
        int c = f >> 5, sq = (f & 31) * 4;
        size_t o = (((size_t)(b * 512 + n0 + c)) << 11) + s0m + sq;
        float4 hv = *(const float4*)(hid + o);
        float4 cv = *(float4*)&Cf[c][sq];
        cv.x += hv.x; cv.y += hv.y; cv.z += hv.z; cv.w += hv.w;
        *(float4*)(out + o) = cv;
    }
}

// ---------------- flash attention: XCD-swizzled grid, raw-exp softmax, setprio ----------------
#define CVTPK(dst, a, b) asm("v_cvt_pk_bf16_f32 %0, %1, %2" : "=v"(dst) : "v"(a), "v"(b))
#define SWAP32(a, b)     asm("v_permlane32_swap_b32 %0, %1" : "+v"(a), "+v"(b))

#define STAGE(buf_, kt_) {                                                    \
    const ushort* g_ = gsrc + (size_t)(kt_) * ktstride;                       \
    ushort* lp_ = ktv + (buf_) * 16384 + wv * 4096;                           \
    _Pragma("unroll")                                                         \
    for (int i_ = 0; i_ < 8; i_++)                                            \
        GLD(g_ + (size_t)i_ * istride, lp_ + i_ * 512); }

__global__ __launch_bounds__(256, 2) void k_attn(const ushort* __restrict__ Qf,
                                                 const ushort* __restrict__ Kf,
                                                 const ushort* __restrict__ Vtg,
                                                 ushort* __restrict__ Ob) {
    __shared__ ushort __attribute__((aligned(16))) ktv[2 * 4 * 4096];   // 64 KB
    __shared__ float mlsh[2][2][2][32];

    // XCD swizzle: all 32 q-blocks of one (h,b) -> same XCD (K/V stays in its 4MB L2)
    const int id = blockIdx.x;                 // 512 blocks
    const int lgc = (id & 7) * 64 + (id >> 3);
    const int qb = lgc & 31;
    const int hb = lgc >> 5;                   // 0..15
    const int hd = hb & 7, b = hb >> 3;

    const int tid = threadIdx.x;
    const int l = tid & 63, wv = tid >> 6;
    const int wp = wv >> 1, hh = wv & 1;
    const int l31 = l & 31, hi = l >> 5, swz = l31 & 7;
    const int hoff = hd * HD_;
    const int brow = b * S_ + qb * 64;

    bfrag qf[4];
    {
        const ushort* qp = Qf + (size_t)(brow + wp * 32 + l31) * INNER_ + hoff + hi * 8;
        #pragma unroll
        for (int ks = 0; ks < 4; ks++) qf[ks] = *(const bfrag*)(qp + ks * 16);
    }

    const int hv = wv >> 1, isV = wv & 1;
    const int rr = l >> 3;
    const int clog = (l & 7) ^ rr;
    const ushort* gsrc;
    size_t istride, ktstride;
    if (isV) {
        gsrc = Vtg + (size_t)(b * 512 + hoff + rr) * 2048 + hv * 1024 + clog * 8;
        istride = (size_t)8 * 2048;
        ktstride = 64;
    } else {
        gsrc = Kf + (size_t)(b * S_ + hv * 1024 + rr) * INNER_ + hoff + clog * 8;
        istride = (size_t)8 * INNER_;
        ktstride = (size_t)64 * INNER_;
    }

    STAGE(0, 0);

    float m_run = -INFINITY, l_run = 0.f;
    f16v acc0 = zero16(), acc1 = zero16();
    int cur = 0;

    for (int kt = 0; kt < 16; kt++) {
        __syncthreads();
        if (kt < 15) STAGE(cur ^ 1, kt + 1);

        const ushort* Kt  = ktv + cur * 16384 + hh * 8192;
        const ushort* Vtt = Kt + 4096;

        f16v sf0 = zero16(), sf1 = zero16();
        __builtin_amdgcn_s_setprio(1);
        #pragma unroll
        for (int ks = 0; ks < 4; ks++) {
            int ch = ((ks * 2 + hi) ^ swz) * 8;
            bfrag k0 = *(const bfrag*)(Kt + l31 * 64 + ch);
            bfrag k1 = *(const bfrag*)(Kt + (l31 + 32) * 64 + ch);
            sf0 = __builtin_amdgcn_mfma_f32_32x32x16_bf16(k0, qf[ks], sf0, 0, 0, 0);
            sf1 = __builtin_amdgcn_mfma_f32_32x32x16_bf16(k1, qf[ks], sf1, 0, 0, 0);
        }
        __builtin_amdgcn_s_setprio(0);

        // online softmax: p = exp2((s - m) * 0.125 * log2e), all in one fma + v_exp
        float tm = -INFINITY;
        #pragma unroll
        for (int j = 0; j < 16; j++) { tm = fmaxf(tm, sf0[j]); tm = fmaxf(tm, sf1[j]); }
        tm = fmaxf(tm, __shfl_xor(tm, 32));
        if (!__all(tm <= m_run + 64.0f)) {     // defer-max: 8 nats in raw units
            float mn = fmaxf(m_run, tm);
            float corr; EXPA(corr, (m_run - mn) * SC_LOG2E);
            l_run *= corr;
            #pragma unroll
            for (int j = 0; j < 16; j++) { acc0[j] *= corr; acc1[j] *= corr; }
            m_run = mn;
        }
        float nm = -m_run * SC_LOG2E;
        float ls = 0.f;
        #pragma unroll
        for (int j = 0; j < 16; j++) { float p; EXPA(p, fmaf(sf0[j], SC_LOG2E, nm)); sf0[j] = p; ls += p; }
        #pragma unroll
        for (int j = 0; j < 16; j++) { float p; EXPA(p, fmaf(sf1[j], SC_LOG2E, nm)); sf1[j] = p; ls += p; }
        ls += __shfl_xor(ls, 32);
        l_run += ls;

        __builtin_amdgcn_s_setprio(1);
        #pragma unroll
        for (int s = 0; s < 2; s++) {
            unsigned A0, B0, A1, B1;
            CVTPK(A0, sf0[s * 8 + 0], sf0[s * 8 + 1]); CVTPK(B0, sf0[s * 8 + 4], sf0[s * 8 + 5]);
            SWAP32(A0, B0);
            CVTPK(A1, sf0[s * 8 + 2], sf0[s * 8 + 3]); CVTPK(B1, sf0[s * 8 + 6], sf0[s * 8 + 7]);
            SWAP32(A1, B1);
            uint4 u; u.x = A0; u.y = A1; u.z = B0; u.w = B1;
            bfrag pa = __builtin_bit_cast(bfrag, u);
            int ch = ((s * 2 + hi) ^ swz) * 8;
            bfrag v0 = *(const bfrag*)(Vtt + l31 * 64 + ch);
            bfrag v1 = *(const bfrag*)(Vtt + (l31 + 32) * 64 + ch);
            acc0 = __builtin_amdgcn_mfma_f32_32x32x16_bf16(v0, pa, acc0, 0, 0, 0);
            acc1 = __builtin_amdgcn_mfma_f32_32x32x16_bf16(v1, pa, acc1, 0, 0, 0);
        }
        #pragma unroll
        for (int s = 0; s < 2; s++) {
            unsigned A0, B0, A1, B1;
            CVTPK(A0, sf1[s * 8 + 0], sf1[s * 8 + 1]); CVTPK(B0, sf1[s * 8 + 4], sf1[s * 8 + 5]);
            SWAP32(A0, B0);
            CVTPK(A1, sf1[s * 8 + 2], sf1[s * 8 + 3]); CVTPK(B1, sf1[s * 8 + 6], sf1[s * 8 + 7]);
            SWAP32(A1, B1);
            uint4 u; u.x = A0; u.y = A1; u.z = B0; u.w = B1;
            bfrag pa = __builtin_bit_cast(bfrag, u);
            int ch = (((2 + s) * 2 + hi) ^ swz) * 8;
            bfrag v0 = *(const bfrag*)(Vtt + l31 * 64 + ch);
            bfrag v1 = *(const bfrag*)(Vtt + (l31 + 32) * 64 + ch);
            acc0 = __builtin_amdgcn_mfma_f32_32x32x16_bf16(v0, pa, acc0, 0, 0, 0);
            acc1 = __builtin_amdgcn_mfma_f32_32x32x16_bf16(v1, pa, acc1, 0, 0, 0);
        }
        __builtin_amdgcn_s_setprio(0);

        cur ^= 1;
    }

    if (l < 32) { mlsh[wp][hh][0][l] = m_run; mlsh[wp][hh][1][l] = l_run; }
    __syncthreads();
    float mo  = mlsh[wp][hh ^ 1][0][l31];
    float lo_ = mlsh[wp][hh ^ 1][1][l31];
    float mn2 = fmaxf(m_run, mo);
    float cs, co;
    EXPA(cs, (m_run - mn2) * SC_LOG2E);
    EXPA(co, (mo    - mn2) * SC_LOG2E);
    float inv = 1.0f / (cs * l_run + co * lo_);

    float* cmb = (float*)ktv;
    if (hh == 0) {
        #pragma unroll
        for (int j = 0; j < 16; j++) {
            int d0 = (j & 3) + 8 * (j >> 2) + 4 * hi;
            cmb[wp * 2112 + d0 * 33 + l31]        = cs * acc0[j];
            cmb[wp * 2112 + (d0 + 32) * 33 + l31] = cs * acc1[j];
        }
    }
    __syncthreads();
    if (hh == 1) {
        #pragma unroll
        for (int j = 0; j < 16; j++) {
            int d0 = (j & 3) + 8 * (j >> 2) + 4 * hi;
            int i0 = wp * 2112 + d0 * 33 + l31;
            int i1 = wp * 2112 + (d0 + 32) * 33 + l31;
            cmb[i0] = (cmb[i0] + cs * acc0[j]) * inv;
            cmb[i1] = (cmb[i1] + cs * acc1[j]) * inv;
        }
    }
    __syncthreads();
    #pragma unroll
    for (int p2 = 0; p2 < 2; p2++) {
        int f = p2 * 256 + tid;
        int q = f >> 3, dc = f & 7;
        int wpp = q >> 5, ql = q & 31;
        bfrag ov;
        #pragma unroll
        for (int j2 = 0; j2 < 8; j2++)
            ov[j2] = (short)f2bf(cmb[wpp * 2112 + (dc * 8 + j2) * 33 + ql]);
        *(uint4*)(Ob + (size_t)(brow + q) * INNER_ + hoff + dc * 8) = __builtin_bit_cast(uint4, ov);
    }
}

extern "C" void kernel_launch(void* const* d_in, const int* in_sizes, int n_in,
                              void* d_out, int out_size, void* d_ws, size_t ws_size,
                              hipStream_t stream) {
    const float* hid  = (const float*)d_in[0];
    const float* Wq   = (const float*)d_in[1];
    const float* Wk   = (const float*)d_in[2];
    const float* Wv   = (const float*)d_in[3];
    const float* Wout = (const float*)d_in[4];
    const float* bout = (const float*)d_in[5];
    float* out = (float*)d_out;

    const int M = B_ * S_;   // 4096
    char* w = (char*)d_ws;
    ushort* X    = (ushort*)w;                    w += (size_t)M * QKC_ * 2;
    ushort* Qb   = (ushort*)w;                    w += (size_t)M * INNER_ * 2;
    ushort* Kbb  = (ushort*)w;                    w += (size_t)M * INNER_ * 2;
    ushort* Vtg  = (ushort*)w;                    w += (size_t)M * INNER_ * 2;   // [B*512][2048]
    ushort* Ob   = (ushort*)w;                    w += (size_t)M * INNER_ * 2;
    ushort* Wqt  = (ushort*)w;                    w += (size_t)INNER_ * QKC_ * 2;
    ushort* Wkt  = (ushort*)w;                    w += (size_t)INNER_ * QKC_ * 2;
    ushort* Wvt  = (ushort*)w;                    w += (size_t)INNER_ * C_ * 2;
    ushort* Wot  = (ushort*)w;                    w += (size_t)C_ * INNER_ * 2;

    k_wtrans_all<<<dim3(18, 16, 4), dim3(32, 32), 0, stream>>>(Wq, Wk, Wv, Wout,
                                                               Wqt, Wkt, Wvt, Wot);
    k_trans_emb<<<dim3(S_ / 32, 18, B_), dim3(32, 32), 0, stream>>>(hid, X);

    k_qkv<<<dim3(768), 256, 0, stream>>>(X, Wqt, Wkt, Wvt, Qb, Kbb, Vtg);

    k_attn<<<dim3(512), 256, 0, stream>>>(Qb, Kbb, Vtg, Ob);

    k_og<<<dim3(256), 256, 0, stream>>>(Ob, Wot, bout, hid, out);
}